// Round 14
// baseline (299.392 us; speedup 1.0000x reference)
//
#include <hip/hip_runtime.h>
#include <hip/hip_bf16.h>

#define HID 128

typedef __attribute__((ext_vector_type(8))) short short8;
typedef __attribute__((ext_vector_type(4))) float f32x4;

__device__ __forceinline__ unsigned short f2bf(float f) {
    unsigned int u = __builtin_bit_cast(unsigned int, f);
    u += 0x7FFFu + ((u >> 16) & 1u);
    return (unsigned short)(u >> 16);
}
__device__ __forceinline__ float bf2f(unsigned short h) {
    unsigned int u = ((unsigned int)h) << 16;
    return __builtin_bit_cast(float, u);
}

// ---------------- prep: W[k][128] f32 -> fragment order Wf[ks][nt][lane][j] bf16 ----------------
__global__ void prep_w(const float* __restrict__ W, unsigned short* __restrict__ Wf, int nks) {
    int t = blockIdx.x * 256 + threadIdx.x;
    if (t >= nks * 8 * 64) return;
    int lane = t & 63, nt = (t >> 6) & 7, ks = t >> 9;
    int kb  = ks * 32 + ((lane >> 4) << 3);
    int col = (nt << 4) + (lane & 15);
    union { unsigned short u[8]; uint4 q; } p;
    #pragma unroll
    for (int j = 0; j < 8; ++j) p.u[j] = f2bf(W[(size_t)(kb + j) * 128 + col]);
    *(uint4*)(Wf + (size_t)t * 8) = p.q;
}

// hi/lo split fragments (plain, for Wu2)
__global__ void prep_w_split(const float* __restrict__ W,
                             unsigned short* __restrict__ Wh,
                             unsigned short* __restrict__ Wl, int nks) {
    int t = blockIdx.x * 256 + threadIdx.x;
    if (t >= nks * 8 * 64) return;
    int lane = t & 63, nt = (t >> 6) & 7, ks = t >> 9;
    int kb  = ks * 32 + ((lane >> 4) << 3);
    int col = (nt << 4) + (lane & 15);
    union { unsigned short u[8]; uint4 q; } ph, pl;
    #pragma unroll
    for (int j = 0; j < 8; ++j) {
        float w = W[(size_t)(kb + j) * 128 + col];
        unsigned short h = f2bf(w);
        ph.u[j] = h;
        pl.u[j] = f2bf(w - bf2f(h));
    }
    *(uint4*)(Wh + (size_t)t * 8) = ph.q;
    *(uint4*)(Wl + (size_t)t * 8) = pl.q;
}

// ---------------- fused: stacked [Wtop(0:128) ; Wm2@Wtop(128:256)] -> hi/lo frags + bias ----------
// Replaces compose_k + bias_comp_k + stack_k + prep_w_split (same fmaf order -> bit-identical).
__global__ void prep_split_comp(const float* __restrict__ Wtop,  // [256][128] (Wg or Wu1)
                                const float* __restrict__ Wm2,   // [128][128]
                                const float* __restrict__ b2,    // [128]
                                unsigned short* __restrict__ Wh,
                                unsigned short* __restrict__ Wl,
                                float* __restrict__ bc)
{
    int t = blockIdx.x * 256 + threadIdx.x;
    if (t < 8 * 8 * 64) {
        int lane = t & 63, nt = (t >> 6) & 7, ks = t >> 9;
        int kb  = ks * 32 + ((lane >> 4) << 3);
        int col = (nt << 4) + (lane & 15);
        union { unsigned short u[8]; uint4 q; } ph, pl;
        #pragma unroll
        for (int j = 0; j < 8; ++j) {
            int r = kb + j;
            float w;
            if (r < 128) {
                w = Wtop[(size_t)r * 128 + col];
            } else {
                const float* a = Wm2 + (size_t)(r - 128) * 128;
                float s = 0.f;
                for (int k = 0; k < 128; ++k)
                    s = fmaf(a[k], Wtop[(size_t)(128 + k) * 128 + col], s);
                w = s;
            }
            unsigned short h = f2bf(w);
            ph.u[j] = h;
            pl.u[j] = f2bf(w - bf2f(h));
        }
        *(uint4*)(Wh + (size_t)t * 8) = ph.q;
        *(uint4*)(Wl + (size_t)t * 8) = pl.q;
    }
    if (blockIdx.x == 0 && threadIdx.x < 128) {
        int j = threadIdx.x;
        float s = 0.f;
        for (int k = 0; k < 128; ++k)
            s = fmaf(b2[k], Wtop[(size_t)(128 + k) * 128 + j], s);
        bc[j] = s;
    }
}

// ---------------- counting sort by dst -> fused 16B edge records ----------------
__global__ void hist_k(const int* __restrict__ ei, unsigned* __restrict__ cnt, int E) {
    int e = blockIdx.x * 256 + threadIdx.x;
    if (e < E) atomicAdd(&cnt[ei[E + e]], 1u);
}

// single-block scan, x4 vectorized (13 iters for N=50k)
__global__ void scan_k(const unsigned* __restrict__ cnt, unsigned* __restrict__ cur, int n) {
    __shared__ unsigned wsum[16];
    int tid = threadIdx.x, lane = tid & 63, w = tid >> 6;
    unsigned carry = 0;
    for (int base = 0; base < n; base += 4096) {
        int i = base + tid * 4;
        unsigned v0 = 0, v1 = 0, v2 = 0, v3 = 0;
        if (i + 3 < n) {
            uint4 q = *(const uint4*)(cnt + i);
            v0 = q.x; v1 = q.y; v2 = q.z; v3 = q.w;
        } else {
            if (i < n)     v0 = cnt[i];
            if (i + 1 < n) v1 = cnt[i + 1];
            if (i + 2 < n) v2 = cnt[i + 2];
            if (i + 3 < n) v3 = cnt[i + 3];
        }
        unsigned t0 = v0, t1 = t0 + v1, t2 = t1 + v2, t3 = t2 + v3;
        unsigned s = t3;
        #pragma unroll
        for (int off = 1; off < 64; off <<= 1) {
            unsigned t = __shfl_up(s, off);
            if (lane >= off) s += t;
        }
        if (lane == 63) wsum[w] = s;
        __syncthreads();
        if (tid < 16) {
            unsigned t = wsum[tid];
            #pragma unroll
            for (int off = 1; off < 16; off <<= 1) {
                unsigned u = __shfl_up(t, off);
                if (tid >= off) t += u;
            }
            wsum[tid] = t;
        }
        __syncthreads();
        unsigned woff = (w == 0) ? 0u : wsum[w - 1];
        unsigned excl = carry + woff + (s - t3);
        if (i < n)     cur[i]     = excl;
        if (i + 1 < n) cur[i + 1] = excl + t0;
        if (i + 2 < n) cur[i + 2] = excl + t1;
        if (i + 3 < n) cur[i + 3] = excl + t2;
        unsigned tot = wsum[15];
        __syncthreads();
        carry += tot;
    }
}

__global__ void scatter_k(const int* __restrict__ ei, const float* __restrict__ ea,
                          unsigned* __restrict__ cur, uint4* __restrict__ rec, int E) {
    int e = blockIdx.x * 256 + threadIdx.x;
    if (e >= E) return;
    int d = ei[E + e];
    unsigned pos = atomicAdd(&cur[d], 1u);
    uint4 r;
    r.x = (unsigned)ei[e];
    r.y = __builtin_bit_cast(unsigned, ea[(size_t)e * 3 + 0]);
    r.z = __builtin_bit_cast(unsigned, ea[(size_t)e * 3 + 1]);
    r.w = __builtin_bit_cast(unsigned, ea[(size_t)e * 3 + 2]);
    rec[pos] = r;
}

// ---------------- S1 = x@W1[:128], T = x@W1[128:256], B from LDS ----------------
__global__ __launch_bounds__(256, 2)
void s1t_gemm(const float* __restrict__ x, const unsigned short* __restrict__ W1f,
              unsigned short* __restrict__ S1b, unsigned short* __restrict__ Tb, int N)
{
    __shared__ alignas(16) unsigned short sW[32768];
    const int tid  = threadIdx.x;
    for (int i = tid; i < 4096; i += 256)
        ((uint4*)sW)[i] = ((const uint4*)W1f)[i];
    __syncthreads();

    const int lane = tid & 63;
    const int wid  = tid >> 6;
    const int n0   = (blockIdx.x * 4 + wid) * 16;
    if (n0 >= N) return;
    const int arow = lane & 15;
    const int g4   = lane >> 4;

    int nr = n0 + arow; if (nr >= N) nr = N - 1;
    const float* px = x + (size_t)nr * 128 + g4 * 8;

    short8 af[4];
    #pragma unroll
    for (int ks = 0; ks < 4; ++ks) {
        float4 v0 = *(const float4*)(px + ks * 32);
        float4 v1 = *(const float4*)(px + ks * 32 + 4);
        float v[8] = { v0.x, v0.y, v0.z, v0.w, v1.x, v1.y, v1.z, v1.w };
        #pragma unroll
        for (int j = 0; j < 8; ++j) af[ks][j] = (short)f2bf(v[j]);
    }

    f32x4 s1[8], tt[8];
    #pragma unroll
    for (int i = 0; i < 8; ++i) { s1[i] = (f32x4)0.f; tt[i] = (f32x4)0.f; }
    #pragma unroll
    for (int ks = 0; ks < 4; ++ks) {
        #pragma unroll
        for (int nt = 0; nt < 8; ++nt) {
            short8 b1 = *(const short8*)(sW + (size_t)((ks * 8 + nt) * 64 + lane) * 8);
            short8 b2 = *(const short8*)(sW + (size_t)(((ks + 4) * 8 + nt) * 64 + lane) * 8);
            s1[nt] = __builtin_amdgcn_mfma_f32_16x16x32_bf16(af[ks], b1, s1[nt], 0, 0, 0);
            tt[nt] = __builtin_amdgcn_mfma_f32_16x16x32_bf16(af[ks], b2, tt[nt], 0, 0, 0);
        }
    }
    #pragma unroll
    for (int nt = 0; nt < 8; ++nt) {
        int col = nt * 16 + arow;
        #pragma unroll
        for (int r = 0; r < 4; ++r) {
            int node = n0 + g4 * 4 + r;
            if (node < N) {
                S1b[(size_t)node * 128 + col] = f2bf(s1[nt][r]);
                Tb [(size_t)node * 128 + col] = f2bf(tt[nt][r]);
            }
        }
    }
}

// ---------------- CSR edge kernel: depth-2 pipelined gather-reduce, zero atomics ----------------
__global__ __launch_bounds__(256, 8)
void csr_edge_k(const unsigned short* __restrict__ S1b, const unsigned short* __restrict__ Tb,
                const uint4* __restrict__ rec,
                const unsigned* __restrict__ cnt, const unsigned* __restrict__ cur,
                const float* __restrict__ W1tail, const float* __restrict__ bm1,
                float* __restrict__ HS, int N)
{
    const int lane = threadIdx.x & 63;
    const int wid  = threadIdx.x >> 6;
    const int gw   = blockIdx.x * 4 + wid;
    const int stride = gridDim.x * 4;
    const int c2 = lane * 2;

    const float w00 = W1tail[c2],       w01 = W1tail[c2 + 1];
    const float w10 = W1tail[128 + c2], w11 = W1tail[128 + c2 + 1];
    const float w20 = W1tail[256 + c2], w21 = W1tail[256 + c2 + 1];
    const float b0  = bm1[c2],          b1v = bm1[c2 + 1];

    for (int d = gw; d < N; d += stride) {
        int e1 = (int)cur[d];
        int c  = (int)cnt[d];
        int e0 = e1 - c;
        unsigned tv = *(const unsigned*)(Tb + (size_t)d * 128 + c2);
        float t0 = bf2f((unsigned short)(tv & 0xffff)) + b0;
        float t1 = bf2f((unsigned short)(tv >> 16))    + b1v;
        float a0 = 0.f, a1 = 0.f;
        if (c > 0) {
            uint4 r0 = rec[e0];
            uint4 r1 = (c > 1) ? rec[e0 + 1] : make_uint4(0u, 0u, 0u, 0u);
            unsigned sv0 = *(const unsigned*)(S1b + (size_t)r0.x * 128 + c2);
            for (int e = e0; e < e1; ++e) {
                uint4 r2 = (e + 2 < e1) ? rec[e + 2] : make_uint4(0u, 0u, 0u, 0u);
                unsigned sv1 = (e + 1 < e1)
                    ? *(const unsigned*)(S1b + (size_t)r1.x * 128 + c2) : 0u;
                float x0 = __builtin_bit_cast(float, r0.y);
                float x1 = __builtin_bit_cast(float, r0.z);
                float x2 = __builtin_bit_cast(float, r0.w);
                float h0 = bf2f((unsigned short)(sv0 & 0xffff)) + t0;
                float h1 = bf2f((unsigned short)(sv0 >> 16))    + t1;
                h0 = fmaf(x0, w00, h0); h0 = fmaf(x1, w10, h0); h0 = fmaf(x2, w20, h0);
                h1 = fmaf(x0, w01, h1); h1 = fmaf(x1, w11, h1); h1 = fmaf(x2, w21, h1);
                a0 += fmaxf(h0, 0.f);
                a1 += fmaxf(h1, 0.f);
                r0 = r1; r1 = r2; sv0 = sv1;
            }
        }
        float2 o; o.x = a0; o.y = a1;
        *(float2*)(HS + (size_t)d * 128 + c2) = o;
    }
}

// tier-B fallback: per-edge atomics from raw inputs (HS pre-zeroed)
__global__ __launch_bounds__(256, 8)
void atomic_edge_k(const unsigned short* __restrict__ S1b, const unsigned short* __restrict__ Tb,
                   const int* __restrict__ ei, const float* __restrict__ ea,
                   const float* __restrict__ W1tail, const float* __restrict__ bm1,
                   float* __restrict__ HS, int E)
{
    const int lane = threadIdx.x & 63;
    const int wid  = threadIdx.x >> 6;
    const int gw   = blockIdx.x * 4 + wid;
    const int stride = gridDim.x * 4;
    const int c2 = lane * 2;

    const float w00 = W1tail[c2],       w01 = W1tail[c2 + 1];
    const float w10 = W1tail[128 + c2], w11 = W1tail[128 + c2 + 1];
    const float w20 = W1tail[256 + c2], w21 = W1tail[256 + c2 + 1];
    const float b0  = bm1[c2],          b1v = bm1[c2 + 1];

    for (int e = gw; e < E; e += stride) {
        int s = ei[e], d = ei[E + e];
        float x0 = ea[(size_t)e * 3 + 0];
        float x1 = ea[(size_t)e * 3 + 1];
        float x2 = ea[(size_t)e * 3 + 2];
        unsigned tv = *(const unsigned*)(Tb + (size_t)d * 128 + c2);
        unsigned sv = *(const unsigned*)(S1b + (size_t)s * 128 + c2);
        float h0 = bf2f((unsigned short)(sv & 0xffff)) + bf2f((unsigned short)(tv & 0xffff)) + b0;
        float h1 = bf2f((unsigned short)(sv >> 16))    + bf2f((unsigned short)(tv >> 16))    + b1v;
        h0 = fmaf(x0, w00, h0); h0 = fmaf(x1, w10, h0); h0 = fmaf(x2, w20, h0);
        h1 = fmaf(x0, w01, h1); h1 = fmaf(x1, w11, h1); h1 = fmaf(x2, w21, h1);
        unsafeAtomicAdd(HS + (size_t)d * 128 + c2,     fmaxf(h0, 0.f));
        unsafeAtomicAdd(HS + (size_t)d * 128 + c2 + 1, fmaxf(h1, 0.f));
    }
}

// ---------------- Node kernel: 2 node-tiles share each staged weight chunk ----------------
__global__ __launch_bounds__(256, 2)
void node_mfma(const float* __restrict__ x,
               const float* __restrict__ HS,
               const unsigned* __restrict__ cnt,
               const float* __restrict__ bcg, const float* __restrict__ bcu,
               const unsigned short* __restrict__ WgH, const unsigned short* __restrict__ WgL,
               const unsigned short* __restrict__ Wu1H, const unsigned short* __restrict__ Wu1L,
               const unsigned short* __restrict__ Wu2H, const unsigned short* __restrict__ Wu2L,
               const float* __restrict__ bg, const float* __restrict__ bu1,
               const float* __restrict__ bu2,
               const float* __restrict__ gamma, const float* __restrict__ beta,
               float* __restrict__ out, int N)
{
    __shared__ alignas(16) unsigned short sB[16384];   // 32 KB weight chunk
    __shared__ alignas(16) char Hs[4][8192];           // 32 KB u1 transpose (one tile at a time)

    const int tid  = threadIdx.x;
    const int lane = tid & 63;
    const int wid  = tid >> 6;
    const int arow = lane & 15;
    const int g4   = lane >> 4;
    const int nb   = blockIdx.x * 128;
    // NO early return: block barriers are cooperative.

    int n0[2] = { nb + wid * 16, nb + 64 + wid * 16 };
    const float* px[2];
    const float* pa[2];
    #pragma unroll
    for (int t = 0; t < 2; ++t) {
        int nr = n0[t] + arow; if (nr >= N) nr = N - 1;
        px[t] = x  + (size_t)nr * 128 + g4 * 8;
        pa[t] = HS + (size_t)nr * 128 + g4 * 8;
    }

    float degf[2][4];
    #pragma unroll
    for (int t = 0; t < 2; ++t)
        #pragma unroll
        for (int r = 0; r < 4; ++r) {
            int node = n0[t] + g4 * 4 + r;
            degf[t][r] = (node < N) ? (float)cnt[node] : 0.f;
        }

    f32x4 ga[2][8], ua[2][8];
    #pragma unroll
    for (int t = 0; t < 2; ++t)
        #pragma unroll
        for (int i = 0; i < 8; ++i) { ga[t][i] = (f32x4)0.f; ua[t][i] = (f32x4)0.f; }

    uint4* sB4 = (uint4*)sB;

    // ---- gate + u1 GEMMs (K=256, 3-pass), 2 tiles share staged chunk ----
    for (int ks = 0; ks < 8; ++ks) {
        float4 av[2][2];
        #pragma unroll
        for (int t = 0; t < 2; ++t) {
            const float* p = (ks < 4) ? (px[t] + ks * 32) : (pa[t] + (ks - 4) * 32);
            av[t][0] = *(const float4*)p;
            av[t][1] = *(const float4*)(p + 4);
        }
        #pragma unroll
        for (int i = 0; i < 2; ++i) {
            int idx = tid + i * 256;
            sB4[idx]        = ((const uint4*)WgH )[ks * 512 + idx];
            sB4[512 + idx]  = ((const uint4*)WgL )[ks * 512 + idx];
            sB4[1024 + idx] = ((const uint4*)Wu1H)[ks * 512 + idx];
            sB4[1536 + idx] = ((const uint4*)Wu1L)[ks * 512 + idx];
        }
        __syncthreads();
        #pragma unroll
        for (int t = 0; t < 2; ++t) {
            float v[8] = { av[t][0].x, av[t][0].y, av[t][0].z, av[t][0].w,
                           av[t][1].x, av[t][1].y, av[t][1].z, av[t][1].w };
            short8 ah, al;
            #pragma unroll
            for (int j = 0; j < 8; ++j) {
                unsigned short h = f2bf(v[j]);
                ah[j] = (short)h;
                al[j] = (short)f2bf(v[j] - bf2f(h));
            }
            #pragma unroll
            for (int nt = 0; nt < 8; ++nt) {
                size_t o = (size_t)(nt * 64 + lane) * 8;
                short8 bh = *(const short8*)(sB + o);
                short8 bl = *(const short8*)(sB + 4096 + o);
                ga[t][nt] = __builtin_amdgcn_mfma_f32_16x16x32_bf16(ah, bh, ga[t][nt], 0, 0, 0);
                ga[t][nt] = __builtin_amdgcn_mfma_f32_16x16x32_bf16(al, bh, ga[t][nt], 0, 0, 0);
                ga[t][nt] = __builtin_amdgcn_mfma_f32_16x16x32_bf16(ah, bl, ga[t][nt], 0, 0, 0);
                short8 uh = *(const short8*)(sB + 8192 + o);
                short8 ul = *(const short8*)(sB + 12288 + o);
                ua[t][nt] = __builtin_amdgcn_mfma_f32_16x16x32_bf16(ah, uh, ua[t][nt], 0, 0, 0);
                ua[t][nt] = __builtin_amdgcn_mfma_f32_16x16x32_bf16(al, uh, ua[t][nt], 0, 0, 0);
                ua[t][nt] = __builtin_amdgcn_mfma_f32_16x16x32_bf16(ah, ul, ua[t][nt], 0, 0, 0);
            }
        }
        __syncthreads();
    }

    // deg-bias + gate sigmoid (all tiles)
    #pragma unroll
    for (int t = 0; t < 2; ++t)
        #pragma unroll
        for (int nt = 0; nt < 8; ++nt) {
            int col = nt * 16 + arow;
            float bgc = bcg[col], buc = bcu[col], b = bg[col];
            #pragma unroll
            for (int r = 0; r < 4; ++r) {
                ua[t][nt][r] = fmaf(degf[t][r], buc, ua[t][nt][r]);
                float gv = fmaf(degf[t][r], bgc, ga[t][nt][r]);
                ga[t][nt][r] = 1.f / (1.f + expf(-(gv + b)));
            }
        }

    // ---- u2 + epilogue per tile (Hs reused; sB re-staged per tile: cheap) ----
    #pragma unroll
    for (int t = 0; t < 2; ++t) {
        // pack relu(ua[t]+bu1) hi/lo into wave-private Hs
        #pragma unroll
        for (int nt = 0; nt < 8; ++nt) {
            int col = nt * 16 + arow;
            float b1 = bu1[col];
            #pragma unroll
            for (int r = 0; r < 4; ++r) {
                int row = g4 * 4 + r;
                float u = fmaxf(ua[t][nt][r] + b1, 0.f);
                unsigned short h = f2bf(u);
                unsigned short l = f2bf(u - bf2f(h));
                unsigned int pk = (unsigned int)h | ((unsigned int)l << 16);
                *(unsigned int*)(&Hs[wid][row * 512 + ((col * 4) ^ ((row & 15) << 4))]) = pk;
            }
        }

        f32x4 u2a[8];
        #pragma unroll
        for (int i = 0; i < 8; ++i) u2a[i] = (f32x4)0.f;

        for (int ks = 0; ks < 4; ++ks) {
            #pragma unroll
            for (int i = 0; i < 2; ++i) {
                int idx = tid + i * 256;
                sB4[idx]       = ((const uint4*)Wu2H)[ks * 512 + idx];
                sB4[512 + idx] = ((const uint4*)Wu2L)[ks * 512 + idx];
            }
            __syncthreads();
            int b0 = ks * 128 + g4 * 32;
            unsigned int q0[4], q1[4];
            *(uint4*)q0 = *(const uint4*)(&Hs[wid][arow * 512 + ( b0       ^ (arow << 4))]);
            *(uint4*)q1 = *(const uint4*)(&Hs[wid][arow * 512 + ((b0 + 16) ^ (arow << 4))]);
            short8 a2h, a2l;
            #pragma unroll
            for (int j = 0; j < 4; ++j) {
                a2h[j]     = (short)(q0[j] & 0xffff);
                a2l[j]     = (short)(q0[j] >> 16);
                a2h[4 + j] = (short)(q1[j] & 0xffff);
                a2l[4 + j] = (short)(q1[j] >> 16);
            }
            #pragma unroll
            for (int nt = 0; nt < 8; ++nt) {
                size_t o = (size_t)(nt * 64 + lane) * 8;
                short8 bh = *(const short8*)(sB + o);
                short8 bl = *(const short8*)(sB + 4096 + o);
                u2a[nt] = __builtin_amdgcn_mfma_f32_16x16x32_bf16(a2h, bh, u2a[nt], 0, 0, 0);
                u2a[nt] = __builtin_amdgcn_mfma_f32_16x16x32_bf16(a2l, bh, u2a[nt], 0, 0, 0);
                u2a[nt] = __builtin_amdgcn_mfma_f32_16x16x32_bf16(a2h, bl, u2a[nt], 0, 0, 0);
            }
            __syncthreads();
        }

        // epilogue tile t: gating + LayerNorm + store
        float s[4]  = {0.f, 0.f, 0.f, 0.f};
        float ss[4] = {0.f, 0.f, 0.f, 0.f};
        #pragma unroll
        for (int nt = 0; nt < 8; ++nt) {
            int col = nt * 16 + arow;
            float b2 = bu2[col];
            #pragma unroll
            for (int r = 0; r < 4; ++r) {
                int node = n0[t] + g4 * 4 + r;
                int nc = (node < N) ? node : 0;
                float xv = x[(size_t)nc * 128 + col];
                float g  = ga[t][nt][r];
                float o  = g * (u2a[nt][r] + b2) + (1.f - g) * xv;
                u2a[nt][r] = o;
                s[r]  += o;
                ss[r] += o * o;
            }
        }
        #pragma unroll
        for (int off = 8; off >= 1; off >>= 1) {
            #pragma unroll
            for (int r = 0; r < 4; ++r) {
                s[r]  += __shfl_xor(s[r],  off);
                ss[r] += __shfl_xor(ss[r], off);
            }
        }
        float mu[4], rstd[4];
        #pragma unroll
        for (int r = 0; r < 4; ++r) {
            mu[r] = s[r] * (1.f / 128.f);
            float var = ss[r] * (1.f / 128.f) - mu[r] * mu[r];
            rstd[r] = rsqrtf(var + 1e-5f);
        }
        #pragma unroll
        for (int nt = 0; nt < 8; ++nt) {
            int col = nt * 16 + arow;
            float gm = gamma[col], bt = beta[col];
            #pragma unroll
            for (int r = 0; r < 4; ++r) {
                int node = n0[t] + g4 * 4 + r;
                if (node < N)
                    out[(size_t)node * 128 + col] = (u2a[nt][r] - mu[r]) * rstd[r] * gm + bt;
            }
        }
    }
}

extern "C" void kernel_launch(void* const* d_in, const int* in_sizes, int n_in,
                              void* d_out, int out_size, void* d_ws, size_t ws_size,
                              hipStream_t stream)
{
    const float* x    = (const float*)d_in[0];
    const int*   ei   = (const int*)  d_in[1];
    const float* ea   = (const float*)d_in[2];
    const float* Wm1  = (const float*)d_in[3];
    const float* bm1  = (const float*)d_in[4];
    const float* Wm2  = (const float*)d_in[5];
    const float* bm2  = (const float*)d_in[6];
    const float* Wg   = (const float*)d_in[7];
    const float* bg   = (const float*)d_in[8];
    const float* Wu1  = (const float*)d_in[9];
    const float* bu1  = (const float*)d_in[10];
    const float* Wu2  = (const float*)d_in[11];
    const float* bu2  = (const float*)d_in[12];
    const float* gmma = (const float*)d_in[13];
    const float* beta = (const float*)d_in[14];
    float* out = (float*)d_out;

    const int N = in_sizes[0] / HID;
    const int E = in_sizes[1] / 2;

    // workspace carve-up
    unsigned short* S1b  = (unsigned short*)d_ws;            // N*128 bf16
    unsigned short* Tb   = S1b + (size_t)N * HID;            // N*128 bf16
    float*          HS   = (float*)(Tb + (size_t)N * HID);   // N*128 f32
    unsigned short* W1f  = (unsigned short*)(HS + (size_t)N * HID); // 32768
    unsigned short* WgH  = W1f + 32768;
    unsigned short* WgL  = WgH + 32768;
    unsigned short* Wu1H = WgL + 32768;
    unsigned short* Wu1L = Wu1H + 32768;
    unsigned short* Wu2H = Wu1L + 32768;
    unsigned short* Wu2L = Wu2H + 16384;
    float*          bcg  = (float*)(Wu2L + 16384);           // 128
    float*          bcu  = bcg + 128;                        // 128
    unsigned*       cnt  = (unsigned*)(bcu + 128);           // N
    unsigned*       cur  = cnt + N;                          // N
    uint4*          rec  = (uint4*)(cur + N);
    rec = (uint4*)(((size_t)rec + 15) & ~(size_t)15);
    size_t need_sort = (size_t)((char*)(rec + E) - (char*)d_ws);
    const bool tierA = (ws_size >= need_sort);

    // weights prep (fused compose+stack+split)
    prep_w<<<dim3(16), dim3(256), 0, stream>>>(Wm1, W1f, 8);
    prep_split_comp<<<dim3(16), dim3(256), 0, stream>>>(Wg,  Wm2, bm2, WgH,  WgL,  bcg);
    prep_split_comp<<<dim3(16), dim3(256), 0, stream>>>(Wu1, Wm2, bm2, Wu1H, Wu1L, bcu);
    prep_w_split<<<dim3(8), dim3(256), 0, stream>>>(Wu2, Wu2H, Wu2L, 4);

    // dense per-node S1/T
    s1t_gemm<<<dim3((N + 63) / 64), dim3(256), 0, stream>>>(x, W1f, S1b, Tb, N);

    // degree histogram
    hipMemsetAsync(cnt, 0, (size_t)N * sizeof(unsigned), stream);
    hist_k<<<dim3((E + 255) / 256), dim3(256), 0, stream>>>(ei, cnt, E);

    if (tierA) {
        scan_k<<<dim3(1), dim3(1024), 0, stream>>>(cnt, cur, N);
        scatter_k<<<dim3((E + 255) / 256), dim3(256), 0, stream>>>(ei, ea, cur, rec, E);
        csr_edge_k<<<dim3(2048), dim3(256), 0, stream>>>(
            S1b, Tb, rec, cnt, cur, Wm1 + 256 * HID, bm1, HS, N);
    } else {
        hipMemsetAsync(HS, 0, (size_t)N * HID * sizeof(float), stream);
        atomic_edge_k<<<dim3(2048), dim3(256), 0, stream>>>(
            S1b, Tb, ei, ea, Wm1 + 256 * HID, bm1, HS, E);
    }

    node_mfma<<<dim3((N + 127) / 128), dim3(256), 0, stream>>>(
        x, HS, cnt, bcg, bcu,
        WgH, WgL, Wu1H, Wu1L, Wu2H, Wu2L,
        bg, bu1, bu2, gmma, beta, out, N);
}

// Round 15
// 272.819 us; speedup vs baseline: 1.0974x; 1.0974x over previous
//
#include <hip/hip_runtime.h>
#include <hip/hip_bf16.h>

#define HID 128

typedef __attribute__((ext_vector_type(8))) short short8;
typedef __attribute__((ext_vector_type(4))) float f32x4;

__device__ __forceinline__ unsigned short f2bf(float f) {
    unsigned int u = __builtin_bit_cast(unsigned int, f);
    u += 0x7FFFu + ((u >> 16) & 1u);
    return (unsigned short)(u >> 16);
}
__device__ __forceinline__ float bf2f(unsigned short h) {
    unsigned int u = ((unsigned int)h) << 16;
    return __builtin_bit_cast(float, u);
}

// ---------------- prep: W[k][128] f32 -> fragment order Wf[ks][nt][lane][j] bf16 ----------------
__global__ void prep_w(const float* __restrict__ W, unsigned short* __restrict__ Wf, int nks) {
    int t = blockIdx.x * 256 + threadIdx.x;
    if (t >= nks * 8 * 64) return;
    int lane = t & 63, nt = (t >> 6) & 7, ks = t >> 9;
    int kb  = ks * 32 + ((lane >> 4) << 3);
    int col = (nt << 4) + (lane & 15);
    union { unsigned short u[8]; uint4 q; } p;
    #pragma unroll
    for (int j = 0; j < 8; ++j) p.u[j] = f2bf(W[(size_t)(kb + j) * 128 + col]);
    *(uint4*)(Wf + (size_t)t * 8) = p.q;
}

// hi/lo split fragments (plain, for Wu2)
__global__ void prep_w_split(const float* __restrict__ W,
                             unsigned short* __restrict__ Wh,
                             unsigned short* __restrict__ Wl, int nks) {
    int t = blockIdx.x * 256 + threadIdx.x;
    if (t >= nks * 8 * 64) return;
    int lane = t & 63, nt = (t >> 6) & 7, ks = t >> 9;
    int kb  = ks * 32 + ((lane >> 4) << 3);
    int col = (nt << 4) + (lane & 15);
    union { unsigned short u[8]; uint4 q; } ph, pl;
    #pragma unroll
    for (int j = 0; j < 8; ++j) {
        float w = W[(size_t)(kb + j) * 128 + col];
        unsigned short h = f2bf(w);
        ph.u[j] = h;
        pl.u[j] = f2bf(w - bf2f(h));
    }
    *(uint4*)(Wh + (size_t)t * 8) = ph.q;
    *(uint4*)(Wl + (size_t)t * 8) = pl.q;
}

// ---------------- fused compose+stack+split, one element per thread (grid 128) ----------------
__global__ void prep_split_comp(const float* __restrict__ Wtop,  // [256][128]
                                const float* __restrict__ Wm2,   // [128][128]
                                const float* __restrict__ b2,    // [128]
                                unsigned short* __restrict__ Wh,
                                unsigned short* __restrict__ Wl,
                                float* __restrict__ bc)
{
    int t = blockIdx.x * 256 + threadIdx.x;
    if (t < 32768) {
        int j = t & 7, lane = (t >> 3) & 63, nt = (t >> 9) & 7, ks = t >> 12;
        int r   = ks * 32 + ((lane >> 4) << 3) + j;
        int col = (nt << 4) + (lane & 15);
        float w;
        if (r < 128) {
            w = Wtop[(size_t)r * 128 + col];
        } else {
            const float* a = Wm2 + (size_t)(r - 128) * 128;
            float s = 0.f;
            for (int k = 0; k < 128; ++k)
                s = fmaf(a[k], Wtop[(size_t)(128 + k) * 128 + col], s);
            w = s;
        }
        unsigned short h = f2bf(w);
        Wh[t] = h;
        Wl[t] = f2bf(w - bf2f(h));
    }
    if (blockIdx.x == 0 && threadIdx.x < 128) {
        int jj = threadIdx.x;
        float s = 0.f;
        for (int k = 0; k < 128; ++k)
            s = fmaf(b2[k], Wtop[(size_t)(128 + k) * 128 + jj], s);
        bc[jj] = s;
    }
}

// ---------------- counting sort by dst -> fused 16B edge records ----------------
__global__ void hist_k(const int* __restrict__ ei, unsigned* __restrict__ cnt, int E) {
    int e = blockIdx.x * 256 + threadIdx.x;
    if (e < E) atomicAdd(&cnt[ei[E + e]], 1u);
}

// single-block scan, x4 vectorized
__global__ void scan_k(const unsigned* __restrict__ cnt, unsigned* __restrict__ cur, int n) {
    __shared__ unsigned wsum[16];
    int tid = threadIdx.x, lane = tid & 63, w = tid >> 6;
    unsigned carry = 0;
    for (int base = 0; base < n; base += 4096) {
        int i = base + tid * 4;
        unsigned v0 = 0, v1 = 0, v2 = 0, v3 = 0;
        if (i + 3 < n) {
            uint4 q = *(const uint4*)(cnt + i);
            v0 = q.x; v1 = q.y; v2 = q.z; v3 = q.w;
        } else {
            if (i < n)     v0 = cnt[i];
            if (i + 1 < n) v1 = cnt[i + 1];
            if (i + 2 < n) v2 = cnt[i + 2];
            if (i + 3 < n) v3 = cnt[i + 3];
        }
        unsigned t0 = v0, t1 = t0 + v1, t2 = t1 + v2, t3 = t2 + v3;
        unsigned s = t3;
        #pragma unroll
        for (int off = 1; off < 64; off <<= 1) {
            unsigned t = __shfl_up(s, off);
            if (lane >= off) s += t;
        }
        if (lane == 63) wsum[w] = s;
        __syncthreads();
        if (tid < 16) {
            unsigned t = wsum[tid];
            #pragma unroll
            for (int off = 1; off < 16; off <<= 1) {
                unsigned u = __shfl_up(t, off);
                if (tid >= off) t += u;
            }
            wsum[tid] = t;
        }
        __syncthreads();
        unsigned woff = (w == 0) ? 0u : wsum[w - 1];
        unsigned excl = carry + woff + (s - t3);
        if (i < n)     cur[i]     = excl;
        if (i + 1 < n) cur[i + 1] = excl + t0;
        if (i + 2 < n) cur[i + 2] = excl + t1;
        if (i + 3 < n) cur[i + 3] = excl + t2;
        unsigned tot = wsum[15];
        __syncthreads();
        carry += tot;
    }
}

__global__ void scatter_k(const int* __restrict__ ei, const float* __restrict__ ea,
                          unsigned* __restrict__ cur, uint4* __restrict__ rec, int E) {
    int e = blockIdx.x * 256 + threadIdx.x;
    if (e >= E) return;
    int d = ei[E + e];
    unsigned pos = atomicAdd(&cur[d], 1u);
    uint4 r;
    r.x = (unsigned)ei[e];
    r.y = __builtin_bit_cast(unsigned, ea[(size_t)e * 3 + 0]);
    r.z = __builtin_bit_cast(unsigned, ea[(size_t)e * 3 + 1]);
    r.w = __builtin_bit_cast(unsigned, ea[(size_t)e * 3 + 2]);
    rec[pos] = r;
}

// ---------------- S1 = x@W1[:128], T = x@W1[128:256], B from LDS ----------------
__global__ __launch_bounds__(256, 2)
void s1t_gemm(const float* __restrict__ x, const unsigned short* __restrict__ W1f,
              unsigned short* __restrict__ S1b, unsigned short* __restrict__ Tb, int N)
{
    __shared__ alignas(16) unsigned short sW[32768];
    const int tid  = threadIdx.x;
    for (int i = tid; i < 4096; i += 256)
        ((uint4*)sW)[i] = ((const uint4*)W1f)[i];
    __syncthreads();

    const int lane = tid & 63;
    const int wid  = tid >> 6;
    const int n0   = (blockIdx.x * 4 + wid) * 16;
    if (n0 >= N) return;
    const int arow = lane & 15;
    const int g4   = lane >> 4;

    int nr = n0 + arow; if (nr >= N) nr = N - 1;
    const float* px = x + (size_t)nr * 128 + g4 * 8;

    short8 af[4];
    #pragma unroll
    for (int ks = 0; ks < 4; ++ks) {
        float4 v0 = *(const float4*)(px + ks * 32);
        float4 v1 = *(const float4*)(px + ks * 32 + 4);
        float v[8] = { v0.x, v0.y, v0.z, v0.w, v1.x, v1.y, v1.z, v1.w };
        #pragma unroll
        for (int j = 0; j < 8; ++j) af[ks][j] = (short)f2bf(v[j]);
    }

    f32x4 s1[8], tt[8];
    #pragma unroll
    for (int i = 0; i < 8; ++i) { s1[i] = (f32x4)0.f; tt[i] = (f32x4)0.f; }
    #pragma unroll
    for (int ks = 0; ks < 4; ++ks) {
        #pragma unroll
        for (int nt = 0; nt < 8; ++nt) {
            short8 b1 = *(const short8*)(sW + (size_t)((ks * 8 + nt) * 64 + lane) * 8);
            short8 b2 = *(const short8*)(sW + (size_t)(((ks + 4) * 8 + nt) * 64 + lane) * 8);
            s1[nt] = __builtin_amdgcn_mfma_f32_16x16x32_bf16(af[ks], b1, s1[nt], 0, 0, 0);
            tt[nt] = __builtin_amdgcn_mfma_f32_16x16x32_bf16(af[ks], b2, tt[nt], 0, 0, 0);
        }
    }
    #pragma unroll
    for (int nt = 0; nt < 8; ++nt) {
        int col = nt * 16 + arow;
        #pragma unroll
        for (int r = 0; r < 4; ++r) {
            int node = n0 + g4 * 4 + r;
            if (node < N) {
                S1b[(size_t)node * 128 + col] = f2bf(s1[nt][r]);
                Tb [(size_t)node * 128 + col] = f2bf(tt[nt][r]);
            }
        }
    }
}

// ---------------- CSR edge kernel: depth-2 pipelined gather-reduce, zero atomics ----------------
__global__ __launch_bounds__(256, 8)
void csr_edge_k(const unsigned short* __restrict__ S1b, const unsigned short* __restrict__ Tb,
                const uint4* __restrict__ rec,
                const unsigned* __restrict__ cnt, const unsigned* __restrict__ cur,
                const float* __restrict__ W1tail, const float* __restrict__ bm1,
                float* __restrict__ HS, int N)
{
    const int lane = threadIdx.x & 63;
    const int wid  = threadIdx.x >> 6;
    const int gw   = blockIdx.x * 4 + wid;
    const int stride = gridDim.x * 4;
    const int c2 = lane * 2;

    const float w00 = W1tail[c2],       w01 = W1tail[c2 + 1];
    const float w10 = W1tail[128 + c2], w11 = W1tail[128 + c2 + 1];
    const float w20 = W1tail[256 + c2], w21 = W1tail[256 + c2 + 1];
    const float b0  = bm1[c2],          b1v = bm1[c2 + 1];

    for (int d = gw; d < N; d += stride) {
        int e1 = (int)cur[d];
        int c  = (int)cnt[d];
        int e0 = e1 - c;
        unsigned tv = *(const unsigned*)(Tb + (size_t)d * 128 + c2);
        float t0 = bf2f((unsigned short)(tv & 0xffff)) + b0;
        float t1 = bf2f((unsigned short)(tv >> 16))    + b1v;
        float a0 = 0.f, a1 = 0.f;
        if (c > 0) {
            uint4 r0 = rec[e0];
            uint4 r1 = (c > 1) ? rec[e0 + 1] : make_uint4(0u, 0u, 0u, 0u);
            unsigned sv0 = *(const unsigned*)(S1b + (size_t)r0.x * 128 + c2);
            for (int e = e0; e < e1; ++e) {
                uint4 r2 = (e + 2 < e1) ? rec[e + 2] : make_uint4(0u, 0u, 0u, 0u);
                unsigned sv1 = (e + 1 < e1)
                    ? *(const unsigned*)(S1b + (size_t)r1.x * 128 + c2) : 0u;
                float x0 = __builtin_bit_cast(float, r0.y);
                float x1 = __builtin_bit_cast(float, r0.z);
                float x2 = __builtin_bit_cast(float, r0.w);
                float h0 = bf2f((unsigned short)(sv0 & 0xffff)) + t0;
                float h1 = bf2f((unsigned short)(sv0 >> 16))    + t1;
                h0 = fmaf(x0, w00, h0); h0 = fmaf(x1, w10, h0); h0 = fmaf(x2, w20, h0);
                h1 = fmaf(x0, w01, h1); h1 = fmaf(x1, w11, h1); h1 = fmaf(x2, w21, h1);
                a0 += fmaxf(h0, 0.f);
                a1 += fmaxf(h1, 0.f);
                r0 = r1; r1 = r2; sv0 = sv1;
            }
        }
        float2 o; o.x = a0; o.y = a1;
        *(float2*)(HS + (size_t)d * 128 + c2) = o;
    }
}

// tier-B fallback: per-edge atomics from raw inputs (HS pre-zeroed)
__global__ __launch_bounds__(256, 8)
void atomic_edge_k(const unsigned short* __restrict__ S1b, const unsigned short* __restrict__ Tb,
                   const int* __restrict__ ei, const float* __restrict__ ea,
                   const float* __restrict__ W1tail, const float* __restrict__ bm1,
                   float* __restrict__ HS, int E)
{
    const int lane = threadIdx.x & 63;
    const int wid  = threadIdx.x >> 6;
    const int gw   = blockIdx.x * 4 + wid;
    const int stride = gridDim.x * 4;
    const int c2 = lane * 2;

    const float w00 = W1tail[c2],       w01 = W1tail[c2 + 1];
    const float w10 = W1tail[128 + c2], w11 = W1tail[128 + c2 + 1];
    const float w20 = W1tail[256 + c2], w21 = W1tail[256 + c2 + 1];
    const float b0  = bm1[c2],          b1v = bm1[c2 + 1];

    for (int e = gw; e < E; e += stride) {
        int s = ei[e], d = ei[E + e];
        float x0 = ea[(size_t)e * 3 + 0];
        float x1 = ea[(size_t)e * 3 + 1];
        float x2 = ea[(size_t)e * 3 + 2];
        unsigned tv = *(const unsigned*)(Tb + (size_t)d * 128 + c2);
        unsigned sv = *(const unsigned*)(S1b + (size_t)s * 128 + c2);
        float h0 = bf2f((unsigned short)(sv & 0xffff)) + bf2f((unsigned short)(tv & 0xffff)) + b0;
        float h1 = bf2f((unsigned short)(sv >> 16))    + bf2f((unsigned short)(tv >> 16))    + b1v;
        h0 = fmaf(x0, w00, h0); h0 = fmaf(x1, w10, h0); h0 = fmaf(x2, w20, h0);
        h1 = fmaf(x0, w01, h1); h1 = fmaf(x1, w11, h1); h1 = fmaf(x2, w21, h1);
        unsafeAtomicAdd(HS + (size_t)d * 128 + c2,     fmaxf(h0, 0.f));
        unsafeAtomicAdd(HS + (size_t)d * 128 + c2 + 1, fmaxf(h1, 0.f));
    }
}

// ---------------- Node kernel: LDS-overlay (48 KB), 3 blocks/CU ----------------
__global__ __launch_bounds__(256, 3)
void node_mfma(const float* __restrict__ x,
               const float* __restrict__ HS,
               const unsigned* __restrict__ cnt,
               const float* __restrict__ bcg, const float* __restrict__ bcu,
               const unsigned short* __restrict__ WgH, const unsigned short* __restrict__ WgL,
               const unsigned short* __restrict__ Wu1H, const unsigned short* __restrict__ Wu1L,
               const unsigned short* __restrict__ Wu2H, const unsigned short* __restrict__ Wu2L,
               const float* __restrict__ bg, const float* __restrict__ bu1,
               const float* __restrict__ bu2,
               const float* __restrict__ gamma, const float* __restrict__ beta,
               float* __restrict__ out, int N)
{
    // [0,32K): gate/u1 weight chunks, later overlaid by Hs (4 waves x 8 KB)
    // [32K,48K): u2 weight chunks
    __shared__ alignas(16) char smem[49152];

    const int tid  = threadIdx.x;
    const int lane = tid & 63;
    const int wid  = tid >> 6;
    const int n0   = (blockIdx.x * 4 + wid) * 16;
    // NO early return: block barriers are cooperative.

    const int arow = lane & 15;
    const int g4   = lane >> 4;

    int nr = n0 + arow; if (nr >= N) nr = N - 1;
    if (nr < 0) nr = 0;
    const float* px = x  + (size_t)nr * 128 + g4 * 8;
    const float* pa = HS + (size_t)nr * 128 + g4 * 8;

    short8 ah[8], al[8];
    #pragma unroll
    for (int ks = 0; ks < 8; ++ks) {
        const float* p = (ks < 4) ? (px + ks * 32) : (pa + (ks - 4) * 32);
        float4 v0 = *(const float4*)p;
        float4 v1 = *(const float4*)(p + 4);
        float v[8] = { v0.x, v0.y, v0.z, v0.w, v1.x, v1.y, v1.z, v1.w };
        #pragma unroll
        for (int j = 0; j < 8; ++j) {
            unsigned short h = f2bf(v[j]);
            ah[ks][j] = (short)h;
            al[ks][j] = (short)f2bf(v[j] - bf2f(h));
        }
    }

    float degf[4];
    #pragma unroll
    for (int r = 0; r < 4; ++r) {
        int node = n0 + g4 * 4 + r;
        degf[r] = (node >= 0 && node < N) ? (float)cnt[node] : 0.f;
    }

    // ---- gate + u1 GEMMs (K=256, 3-pass), weights staged per ks into smem[0:32K) ----
    f32x4 ga[8], ua[8];
    #pragma unroll
    for (int i = 0; i < 8; ++i) { ga[i] = (f32x4)0.f; ua[i] = (f32x4)0.f; }

    uint4* sB4 = (uint4*)smem;
    const unsigned short* sB = (const unsigned short*)smem;
    for (int ks = 0; ks < 8; ++ks) {
        #pragma unroll
        for (int i = 0; i < 2; ++i) {
            int idx = tid + i * 256;
            sB4[idx]        = ((const uint4*)WgH )[ks * 512 + idx];
            sB4[512 + idx]  = ((const uint4*)WgL )[ks * 512 + idx];
            sB4[1024 + idx] = ((const uint4*)Wu1H)[ks * 512 + idx];
            sB4[1536 + idx] = ((const uint4*)Wu1L)[ks * 512 + idx];
        }
        __syncthreads();
        #pragma unroll
        for (int nt = 0; nt < 8; ++nt) {
            size_t o = (size_t)(nt * 64 + lane) * 8;
            short8 bh = *(const short8*)(sB + o);
            short8 bl = *(const short8*)(sB + 4096 + o);
            ga[nt] = __builtin_amdgcn_mfma_f32_16x16x32_bf16(ah[ks], bh, ga[nt], 0, 0, 0);
            ga[nt] = __builtin_amdgcn_mfma_f32_16x16x32_bf16(al[ks], bh, ga[nt], 0, 0, 0);
            ga[nt] = __builtin_amdgcn_mfma_f32_16x16x32_bf16(ah[ks], bl, ga[nt], 0, 0, 0);
            short8 uh = *(const short8*)(sB + 8192 + o);
            short8 ul = *(const short8*)(sB + 12288 + o);
            ua[nt] = __builtin_amdgcn_mfma_f32_16x16x32_bf16(ah[ks], uh, ua[nt], 0, 0, 0);
            ua[nt] = __builtin_amdgcn_mfma_f32_16x16x32_bf16(al[ks], uh, ua[nt], 0, 0, 0);
            ua[nt] = __builtin_amdgcn_mfma_f32_16x16x32_bf16(ah[ks], ul, ua[nt], 0, 0, 0);
        }
        __syncthreads();   // all reads of this chunk complete before next stage / Hs overlay
    }

    // + deg * composed-bias terms
    #pragma unroll
    for (int nt = 0; nt < 8; ++nt) {
        int col = nt * 16 + arow;
        float bgc = bcg[col], buc = bcu[col];
        #pragma unroll
        for (int r = 0; r < 4; ++r) {
            ga[nt][r] = fmaf(degf[r], bgc, ga[nt][r]);
            ua[nt][r] = fmaf(degf[r], buc, ua[nt][r]);
        }
    }

    // relu + bias, hi/lo pack into wave-private Hs (overlays smem[0:32K))
    char* Hw = smem + wid * 8192;
    #pragma unroll
    for (int nt = 0; nt < 8; ++nt) {
        int col = nt * 16 + arow;
        float b1 = bu1[col];
        #pragma unroll
        for (int r = 0; r < 4; ++r) {
            int row = g4 * 4 + r;
            float u = fmaxf(ua[nt][r] + b1, 0.f);
            unsigned short h = f2bf(u);
            unsigned short l = f2bf(u - bf2f(h));
            unsigned int pk = (unsigned int)h | ((unsigned int)l << 16);
            *(unsigned int*)(Hw + row * 512 + ((col * 4) ^ ((row & 15) << 4))) = pk;
        }
    }

    // gate sigmoid
    #pragma unroll
    for (int nt = 0; nt < 8; ++nt) {
        int col = nt * 16 + arow;
        float b = bg[col];
        #pragma unroll
        for (int r = 0; r < 4; ++r)
            ga[nt][r] = 1.f / (1.f + expf(-(ga[nt][r] + b)));
    }
    __syncthreads();

    // ---- u2 GEMM (K=128, 3-pass), weights staged per ks into smem[32K:48K) ----
    uint4* sC4 = (uint4*)(smem + 32768);
    const unsigned short* sC = (const unsigned short*)(smem + 32768);
    f32x4 u2[8];
    #pragma unroll
    for (int i = 0; i < 8; ++i) u2[i] = (f32x4)0.f;
    for (int ks = 0; ks < 4; ++ks) {
        #pragma unroll
        for (int i = 0; i < 2; ++i) {
            int idx = tid + i * 256;
            sC4[idx]       = ((const uint4*)Wu2H)[ks * 512 + idx];
            sC4[512 + idx] = ((const uint4*)Wu2L)[ks * 512 + idx];
        }
        __syncthreads();
        int b0 = ks * 128 + g4 * 32;
        unsigned int q0[4], q1[4];
        *(uint4*)q0 = *(const uint4*)(Hw + arow * 512 + ( b0       ^ (arow << 4)));
        *(uint4*)q1 = *(const uint4*)(Hw + arow * 512 + ((b0 + 16) ^ (arow << 4)));
        short8 a2h, a2l;
        #pragma unroll
        for (int j = 0; j < 4; ++j) {
            a2h[j]     = (short)(q0[j] & 0xffff);
            a2l[j]     = (short)(q0[j] >> 16);
            a2h[4 + j] = (short)(q1[j] & 0xffff);
            a2l[4 + j] = (short)(q1[j] >> 16);
        }
        #pragma unroll
        for (int nt = 0; nt < 8; ++nt) {
            size_t o = (size_t)(nt * 64 + lane) * 8;
            short8 bh = *(const short8*)(sC + o);
            short8 bl = *(const short8*)(sC + 4096 + o);
            u2[nt] = __builtin_amdgcn_mfma_f32_16x16x32_bf16(a2h, bh, u2[nt], 0, 0, 0);
            u2[nt] = __builtin_amdgcn_mfma_f32_16x16x32_bf16(a2l, bh, u2[nt], 0, 0, 0);
            u2[nt] = __builtin_amdgcn_mfma_f32_16x16x32_bf16(a2h, bl, u2[nt], 0, 0, 0);
        }
        __syncthreads();
    }

    // ---- epilogue: gating + LayerNorm + store ----
    float s[4]  = {0.f, 0.f, 0.f, 0.f};
    float ss[4] = {0.f, 0.f, 0.f, 0.f};
    #pragma unroll
    for (int nt = 0; nt < 8; ++nt) {
        int col = nt * 16 + arow;
        float b2 = bu2[col];
        #pragma unroll
        for (int r = 0; r < 4; ++r) {
            int node = n0 + g4 * 4 + r;
            int nc = (node >= 0 && node < N) ? node : 0;
            float xv = x[(size_t)nc * 128 + col];
            float g  = ga[nt][r];
            float o  = g * (u2[nt][r] + b2) + (1.f - g) * xv;
            u2[nt][r] = o;
            s[r]  += o;
            ss[r] += o * o;
        }
    }
    #pragma unroll
    for (int off = 8; off >= 1; off >>= 1) {
        #pragma unroll
        for (int r = 0; r < 4; ++r) {
            s[r]  += __shfl_xor(s[r],  off);
            ss[r] += __shfl_xor(ss[r], off);
        }
    }
    float mu[4], rstd[4];
    #pragma unroll
    for (int r = 0; r < 4; ++r) {
        mu[r] = s[r] * (1.f / 128.f);
        float var = ss[r] * (1.f / 128.f) - mu[r] * mu[r];
        rstd[r] = rsqrtf(var + 1e-5f);
    }
    #pragma unroll
    for (int nt = 0; nt < 8; ++nt) {
        int col = nt * 16 + arow;
        float gm = gamma[col], bt = beta[col];
        #pragma unroll
        for (int r = 0; r < 4; ++r) {
            int node = n0 + g4 * 4 + r;
            if (node >= 0 && node < N)
                out[(size_t)node * 128 + col] = (u2[nt][r] - mu[r]) * rstd[r] * gm + bt;
        }
    }
}

extern "C" void kernel_launch(void* const* d_in, const int* in_sizes, int n_in,
                              void* d_out, int out_size, void* d_ws, size_t ws_size,
                              hipStream_t stream)
{
    const float* x    = (const float*)d_in[0];
    const int*   ei   = (const int*)  d_in[1];
    const float* ea   = (const float*)d_in[2];
    const float* Wm1  = (const float*)d_in[3];
    const float* bm1  = (const float*)d_in[4];
    const float* Wm2  = (const float*)d_in[5];
    const float* bm2  = (const float*)d_in[6];
    const float* Wg   = (const float*)d_in[7];
    const float* bg   = (const float*)d_in[8];
    const float* Wu1  = (const float*)d_in[9];
    const float* bu1  = (const float*)d_in[10];
    const float* Wu2  = (const float*)d_in[11];
    const float* bu2  = (const float*)d_in[12];
    const float* gmma = (const float*)d_in[13];
    const float* beta = (const float*)d_in[14];
    float* out = (float*)d_out;

    const int N = in_sizes[0] / HID;
    const int E = in_sizes[1] / 2;

    // workspace carve-up
    unsigned short* S1b  = (unsigned short*)d_ws;            // N*128 bf16
    unsigned short* Tb   = S1b + (size_t)N * HID;            // N*128 bf16
    float*          HS   = (float*)(Tb + (size_t)N * HID);   // N*128 f32
    unsigned short* W1f  = (unsigned short*)(HS + (size_t)N * HID); // 32768
    unsigned short* WgH  = W1f + 32768;
    unsigned short* WgL  = WgH + 32768;
    unsigned short* Wu1H = WgL + 32768;
    unsigned short* Wu1L = Wu1H + 32768;
    unsigned short* Wu2H = Wu1L + 32768;
    unsigned short* Wu2L = Wu2H + 16384;
    float*          bcg  = (float*)(Wu2L + 16384);           // 128
    float*          bcu  = bcg + 128;                        // 128
    unsigned*       cnt  = (unsigned*)(bcu + 128);           // N
    unsigned*       cur  = cnt + N;                          // N
    uint4*          rec  = (uint4*)(cur + N);
    rec = (uint4*)(((size_t)rec + 15) & ~(size_t)15);
    size_t need_sort = (size_t)((char*)(rec + E) - (char*)d_ws);
    const bool tierA = (ws_size >= need_sort);

    // weights prep
    prep_w<<<dim3(16), dim3(256), 0, stream>>>(Wm1, W1f, 8);
    prep_split_comp<<<dim3(128), dim3(256), 0, stream>>>(Wg,  Wm2, bm2, WgH,  WgL,  bcg);
    prep_split_comp<<<dim3(128), dim3(256), 0, stream>>>(Wu1, Wm2, bm2, Wu1H, Wu1L, bcu);
    prep_w_split<<<dim3(8), dim3(256), 0, stream>>>(Wu2, Wu2H, Wu2L, 4);

    // dense per-node S1/T
    s1t_gemm<<<dim3((N + 63) / 64), dim3(256), 0, stream>>>(x, W1f, S1b, Tb, N);

    // degree histogram
    hipMemsetAsync(cnt, 0, (size_t)N * sizeof(unsigned), stream);
    hist_k<<<dim3((E + 255) / 256), dim3(256), 0, stream>>>(ei, cnt, E);

    if (tierA) {
        scan_k<<<dim3(1), dim3(1024), 0, stream>>>(cnt, cur, N);
        scatter_k<<<dim3((E + 255) / 256), dim3(256), 0, stream>>>(ei, ea, cur, rec, E);
        csr_edge_k<<<dim3(2048), dim3(256), 0, stream>>>(
            S1b, Tb, rec, cnt, cur, Wm1 + 256 * HID, bm1, HS, N);
    } else {
        hipMemsetAsync(HS, 0, (size_t)N * HID * sizeof(float), stream);
        atomic_edge_k<<<dim3(2048), dim3(256), 0, stream>>>(
            S1b, Tb, ei, ea, Wm1 + 256 * HID, bm1, HS, E);
    }

    node_mfma<<<dim3((N + 63) / 64), dim3(256), 0, stream>>>(
        x, HS, cnt, bcg, bcu,
        WgH, WgL, Wu1H, Wu1L, Wu2H, Wu2L,
        bg, bu1, bu2, gmma, beta, out, N);
}

// Round 16
// 253.378 us; speedup vs baseline: 1.1816x; 1.0767x over previous
//
#include <hip/hip_runtime.h>
#include <hip/hip_bf16.h>

#define HID 128

typedef __attribute__((ext_vector_type(8))) short short8;
typedef __attribute__((ext_vector_type(4))) float f32x4;

__device__ __forceinline__ unsigned short f2bf(float f) {
    unsigned int u = __builtin_bit_cast(unsigned int, f);
    u += 0x7FFFu + ((u >> 16) & 1u);
    return (unsigned short)(u >> 16);
}
__device__ __forceinline__ float bf2f(unsigned short h) {
    unsigned int u = ((unsigned int)h) << 16;
    return __builtin_bit_cast(float, u);
}

// ---------------- prep: W[k][128] f32 -> fragment order Wf[ks][nt][lane][j] bf16 ----------------
__global__ void prep_w(const float* __restrict__ W, unsigned short* __restrict__ Wf, int nks) {
    int t = blockIdx.x * 256 + threadIdx.x;
    if (t >= nks * 8 * 64) return;
    int lane = t & 63, nt = (t >> 6) & 7, ks = t >> 9;
    int kb  = ks * 32 + ((lane >> 4) << 3);
    int col = (nt << 4) + (lane & 15);
    union { unsigned short u[8]; uint4 q; } p;
    #pragma unroll
    for (int j = 0; j < 8; ++j) p.u[j] = f2bf(W[(size_t)(kb + j) * 128 + col]);
    *(uint4*)(Wf + (size_t)t * 8) = p.q;
}

// hi/lo split fragments (plain, for Wu2)
__global__ void prep_w_split(const float* __restrict__ W,
                             unsigned short* __restrict__ Wh,
                             unsigned short* __restrict__ Wl, int nks) {
    int t = blockIdx.x * 256 + threadIdx.x;
    if (t >= nks * 8 * 64) return;
    int lane = t & 63, nt = (t >> 6) & 7, ks = t >> 9;
    int kb  = ks * 32 + ((lane >> 4) << 3);
    int col = (nt << 4) + (lane & 15);
    union { unsigned short u[8]; uint4 q; } ph, pl;
    #pragma unroll
    for (int j = 0; j < 8; ++j) {
        float w = W[(size_t)(kb + j) * 128 + col];
        unsigned short h = f2bf(w);
        ph.u[j] = h;
        pl.u[j] = f2bf(w - bf2f(h));
    }
    *(uint4*)(Wh + (size_t)t * 8) = ph.q;
    *(uint4*)(Wl + (size_t)t * 8) = pl.q;
}

// ---------------- fused compose+stack+split, one element per thread (grid 128) ----------------
__global__ void prep_split_comp(const float* __restrict__ Wtop,  // [256][128]
                                const float* __restrict__ Wm2,   // [128][128]
                                const float* __restrict__ b2,    // [128]
                                unsigned short* __restrict__ Wh,
                                unsigned short* __restrict__ Wl,
                                float* __restrict__ bc)
{
    int t = blockIdx.x * 256 + threadIdx.x;
    if (t < 32768) {
        int j = t & 7, lane = (t >> 3) & 63, nt = (t >> 9) & 7, ks = t >> 12;
        int r   = ks * 32 + ((lane >> 4) << 3) + j;
        int col = (nt << 4) + (lane & 15);
        float w;
        if (r < 128) {
            w = Wtop[(size_t)r * 128 + col];
        } else {
            const float* a = Wm2 + (size_t)(r - 128) * 128;
            float s = 0.f;
            for (int k = 0; k < 128; ++k)
                s = fmaf(a[k], Wtop[(size_t)(128 + k) * 128 + col], s);
            w = s;
        }
        unsigned short h = f2bf(w);
        Wh[t] = h;
        Wl[t] = f2bf(w - bf2f(h));
    }
    if (blockIdx.x == 0 && threadIdx.x < 128) {
        int jj = threadIdx.x;
        float s = 0.f;
        for (int k = 0; k < 128; ++k)
            s = fmaf(b2[k], Wtop[(size_t)(128 + k) * 128 + jj], s);
        bc[jj] = s;
    }
}

// ---------------- counting sort by dst -> fused 16B edge records ----------------
__global__ void hist_k(const int* __restrict__ ei, unsigned* __restrict__ cnt, int E) {
    int e = blockIdx.x * 256 + threadIdx.x;
    if (e < E) atomicAdd(&cnt[ei[E + e]], 1u);
}

// single-block scan, x4 vectorized
__global__ void scan_k(const unsigned* __restrict__ cnt, unsigned* __restrict__ cur, int n) {
    __shared__ unsigned wsum[16];
    int tid = threadIdx.x, lane = tid & 63, w = tid >> 6;
    unsigned carry = 0;
    for (int base = 0; base < n; base += 4096) {
        int i = base + tid * 4;
        unsigned v0 = 0, v1 = 0, v2 = 0, v3 = 0;
        if (i + 3 < n) {
            uint4 q = *(const uint4*)(cnt + i);
            v0 = q.x; v1 = q.y; v2 = q.z; v3 = q.w;
        } else {
            if (i < n)     v0 = cnt[i];
            if (i + 1 < n) v1 = cnt[i + 1];
            if (i + 2 < n) v2 = cnt[i + 2];
            if (i + 3 < n) v3 = cnt[i + 3];
        }
        unsigned t0 = v0, t1 = t0 + v1, t2 = t1 + v2, t3 = t2 + v3;
        unsigned s = t3;
        #pragma unroll
        for (int off = 1; off < 64; off <<= 1) {
            unsigned t = __shfl_up(s, off);
            if (lane >= off) s += t;
        }
        if (lane == 63) wsum[w] = s;
        __syncthreads();
        if (tid < 16) {
            unsigned t = wsum[tid];
            #pragma unroll
            for (int off = 1; off < 16; off <<= 1) {
                unsigned u = __shfl_up(t, off);
                if (tid >= off) t += u;
            }
            wsum[tid] = t;
        }
        __syncthreads();
        unsigned woff = (w == 0) ? 0u : wsum[w - 1];
        unsigned excl = carry + woff + (s - t3);
        if (i < n)     cur[i]     = excl;
        if (i + 1 < n) cur[i + 1] = excl + t0;
        if (i + 2 < n) cur[i + 2] = excl + t1;
        if (i + 3 < n) cur[i + 3] = excl + t2;
        unsigned tot = wsum[15];
        __syncthreads();
        carry += tot;
    }
}

__global__ void scatter_k(const int* __restrict__ ei, const float* __restrict__ ea,
                          unsigned* __restrict__ cur, uint4* __restrict__ rec, int E) {
    int e = blockIdx.x * 256 + threadIdx.x;
    if (e >= E) return;
    int d = ei[E + e];
    unsigned pos = atomicAdd(&cur[d], 1u);
    uint4 r;
    r.x = (unsigned)ei[e];
    r.y = __builtin_bit_cast(unsigned, ea[(size_t)e * 3 + 0]);
    r.z = __builtin_bit_cast(unsigned, ea[(size_t)e * 3 + 1]);
    r.w = __builtin_bit_cast(unsigned, ea[(size_t)e * 3 + 2]);
    rec[pos] = r;
}

// ---------------- S1 = x@W1[:128], T = x@W1[128:256], B from LDS ----------------
__global__ __launch_bounds__(256, 2)
void s1t_gemm(const float* __restrict__ x, const unsigned short* __restrict__ W1f,
              unsigned short* __restrict__ S1b, unsigned short* __restrict__ Tb, int N)
{
    __shared__ alignas(16) unsigned short sW[32768];
    const int tid  = threadIdx.x;
    for (int i = tid; i < 4096; i += 256)
        ((uint4*)sW)[i] = ((const uint4*)W1f)[i];
    __syncthreads();

    const int lane = tid & 63;
    const int wid  = tid >> 6;
    const int n0   = (blockIdx.x * 4 + wid) * 16;
    if (n0 >= N) return;
    const int arow = lane & 15;
    const int g4   = lane >> 4;

    int nr = n0 + arow; if (nr >= N) nr = N - 1;
    const float* px = x + (size_t)nr * 128 + g4 * 8;

    short8 af[4];
    #pragma unroll
    for (int ks = 0; ks < 4; ++ks) {
        float4 v0 = *(const float4*)(px + ks * 32);
        float4 v1 = *(const float4*)(px + ks * 32 + 4);
        float v[8] = { v0.x, v0.y, v0.z, v0.w, v1.x, v1.y, v1.z, v1.w };
        #pragma unroll
        for (int j = 0; j < 8; ++j) af[ks][j] = (short)f2bf(v[j]);
    }

    f32x4 s1[8], tt[8];
    #pragma unroll
    for (int i = 0; i < 8; ++i) { s1[i] = (f32x4)0.f; tt[i] = (f32x4)0.f; }
    #pragma unroll
    for (int ks = 0; ks < 4; ++ks) {
        #pragma unroll
        for (int nt = 0; nt < 8; ++nt) {
            short8 b1 = *(const short8*)(sW + (size_t)((ks * 8 + nt) * 64 + lane) * 8);
            short8 b2 = *(const short8*)(sW + (size_t)(((ks + 4) * 8 + nt) * 64 + lane) * 8);
            s1[nt] = __builtin_amdgcn_mfma_f32_16x16x32_bf16(af[ks], b1, s1[nt], 0, 0, 0);
            tt[nt] = __builtin_amdgcn_mfma_f32_16x16x32_bf16(af[ks], b2, tt[nt], 0, 0, 0);
        }
    }
    #pragma unroll
    for (int nt = 0; nt < 8; ++nt) {
        int col = nt * 16 + arow;
        #pragma unroll
        for (int r = 0; r < 4; ++r) {
            int node = n0 + g4 * 4 + r;
            if (node < N) {
                S1b[(size_t)node * 128 + col] = f2bf(s1[nt][r]);
                Tb [(size_t)node * 128 + col] = f2bf(tt[nt][r]);
            }
        }
    }
}

// ---------------- CSR edge kernel: depth-2 pipelined gather-reduce, zero atomics ----------------
__global__ __launch_bounds__(256, 8)
void csr_edge_k(const unsigned short* __restrict__ S1b, const unsigned short* __restrict__ Tb,
                const uint4* __restrict__ rec,
                const unsigned* __restrict__ cnt, const unsigned* __restrict__ cur,
                const float* __restrict__ W1tail, const float* __restrict__ bm1,
                float* __restrict__ HS, int N)
{
    const int lane = threadIdx.x & 63;
    const int wid  = threadIdx.x >> 6;
    const int gw   = blockIdx.x * 4 + wid;
    const int stride = gridDim.x * 4;
    const int c2 = lane * 2;

    const float w00 = W1tail[c2],       w01 = W1tail[c2 + 1];
    const float w10 = W1tail[128 + c2], w11 = W1tail[128 + c2 + 1];
    const float w20 = W1tail[256 + c2], w21 = W1tail[256 + c2 + 1];
    const float b0  = bm1[c2],          b1v = bm1[c2 + 1];

    for (int d = gw; d < N; d += stride) {
        int e1 = (int)cur[d];
        int c  = (int)cnt[d];
        int e0 = e1 - c;
        unsigned tv = *(const unsigned*)(Tb + (size_t)d * 128 + c2);
        float t0 = bf2f((unsigned short)(tv & 0xffff)) + b0;
        float t1 = bf2f((unsigned short)(tv >> 16))    + b1v;
        float a0 = 0.f, a1 = 0.f;
        if (c > 0) {
            uint4 r0 = rec[e0];
            uint4 r1 = (c > 1) ? rec[e0 + 1] : make_uint4(0u, 0u, 0u, 0u);
            unsigned sv0 = *(const unsigned*)(S1b + (size_t)r0.x * 128 + c2);
            for (int e = e0; e < e1; ++e) {
                uint4 r2 = (e + 2 < e1) ? rec[e + 2] : make_uint4(0u, 0u, 0u, 0u);
                unsigned sv1 = (e + 1 < e1)
                    ? *(const unsigned*)(S1b + (size_t)r1.x * 128 + c2) : 0u;
                float x0 = __builtin_bit_cast(float, r0.y);
                float x1 = __builtin_bit_cast(float, r0.z);
                float x2 = __builtin_bit_cast(float, r0.w);
                float h0 = bf2f((unsigned short)(sv0 & 0xffff)) + t0;
                float h1 = bf2f((unsigned short)(sv0 >> 16))    + t1;
                h0 = fmaf(x0, w00, h0); h0 = fmaf(x1, w10, h0); h0 = fmaf(x2, w20, h0);
                h1 = fmaf(x0, w01, h1); h1 = fmaf(x1, w11, h1); h1 = fmaf(x2, w21, h1);
                a0 += fmaxf(h0, 0.f);
                a1 += fmaxf(h1, 0.f);
                r0 = r1; r1 = r2; sv0 = sv1;
            }
        }
        float2 o; o.x = a0; o.y = a1;
        *(float2*)(HS + (size_t)d * 128 + c2) = o;
    }
}

// tier-B fallback: per-edge atomics from raw inputs (HS pre-zeroed)
__global__ __launch_bounds__(256, 8)
void atomic_edge_k(const unsigned short* __restrict__ S1b, const unsigned short* __restrict__ Tb,
                   const int* __restrict__ ei, const float* __restrict__ ea,
                   const float* __restrict__ W1tail, const float* __restrict__ bm1,
                   float* __restrict__ HS, int E)
{
    const int lane = threadIdx.x & 63;
    const int wid  = threadIdx.x >> 6;
    const int gw   = blockIdx.x * 4 + wid;
    const int stride = gridDim.x * 4;
    const int c2 = lane * 2;

    const float w00 = W1tail[c2],       w01 = W1tail[c2 + 1];
    const float w10 = W1tail[128 + c2], w11 = W1tail[128 + c2 + 1];
    const float w20 = W1tail[256 + c2], w21 = W1tail[256 + c2 + 1];
    const float b0  = bm1[c2],          b1v = bm1[c2 + 1];

    for (int e = gw; e < E; e += stride) {
        int s = ei[e], d = ei[E + e];
        float x0 = ea[(size_t)e * 3 + 0];
        float x1 = ea[(size_t)e * 3 + 1];
        float x2 = ea[(size_t)e * 3 + 2];
        unsigned tv = *(const unsigned*)(Tb + (size_t)d * 128 + c2);
        unsigned sv = *(const unsigned*)(S1b + (size_t)s * 128 + c2);
        float h0 = bf2f((unsigned short)(sv & 0xffff)) + bf2f((unsigned short)(tv & 0xffff)) + b0;
        float h1 = bf2f((unsigned short)(sv >> 16))    + bf2f((unsigned short)(tv >> 16))    + b1v;
        h0 = fmaf(x0, w00, h0); h0 = fmaf(x1, w10, h0); h0 = fmaf(x2, w20, h0);
        h1 = fmaf(x0, w01, h1); h1 = fmaf(x1, w11, h1); h1 = fmaf(x2, w21, h1);
        unsafeAtomicAdd(HS + (size_t)d * 128 + c2,     fmaxf(h0, 0.f));
        unsafeAtomicAdd(HS + (size_t)d * 128 + c2 + 1, fmaxf(h1, 0.f));
    }
}

// ---------------- Node kernel: LDS-overlay (48 KB), no VGPR clamp (HW gives 3 blocks/CU) -------
__global__ __launch_bounds__(256, 2)
void node_mfma(const float* __restrict__ x,
               const float* __restrict__ HS,
               const unsigned* __restrict__ cnt,
               const float* __restrict__ bcg, const float* __restrict__ bcu,
               const unsigned short* __restrict__ WgH, const unsigned short* __restrict__ WgL,
               const unsigned short* __restrict__ Wu1H, const unsigned short* __restrict__ Wu1L,
               const unsigned short* __restrict__ Wu2H, const unsigned short* __restrict__ Wu2L,
               const float* __restrict__ bg, const float* __restrict__ bu1,
               const float* __restrict__ bu2,
               const float* __restrict__ gamma, const float* __restrict__ beta,
               float* __restrict__ out, int N)
{
    // [0,32K): gate/u1 weight chunks, later overlaid by Hs (4 waves x 8 KB)
    // [32K,48K): u2 weight chunks
    __shared__ alignas(16) char smem[49152];

    const int tid  = threadIdx.x;
    const int lane = tid & 63;
    const int wid  = tid >> 6;
    const int n0   = (blockIdx.x * 4 + wid) * 16;
    // NO early return: block barriers are cooperative.

    const int arow = lane & 15;
    const int g4   = lane >> 4;

    int nr = n0 + arow; if (nr >= N) nr = N - 1;
    if (nr < 0) nr = 0;
    const float* px = x  + (size_t)nr * 128 + g4 * 8;
    const float* pa = HS + (size_t)nr * 128 + g4 * 8;

    short8 ah[8], al[8];
    #pragma unroll
    for (int ks = 0; ks < 8; ++ks) {
        const float* p = (ks < 4) ? (px + ks * 32) : (pa + (ks - 4) * 32);
        float4 v0 = *(const float4*)p;
        float4 v1 = *(const float4*)(p + 4);
        float v[8] = { v0.x, v0.y, v0.z, v0.w, v1.x, v1.y, v1.z, v1.w };
        #pragma unroll
        for (int j = 0; j < 8; ++j) {
            unsigned short h = f2bf(v[j]);
            ah[ks][j] = (short)h;
            al[ks][j] = (short)f2bf(v[j] - bf2f(h));
        }
    }

    float degf[4];
    #pragma unroll
    for (int r = 0; r < 4; ++r) {
        int node = n0 + g4 * 4 + r;
        degf[r] = (node >= 0 && node < N) ? (float)cnt[node] : 0.f;
    }

    // ---- gate + u1 GEMMs (K=256, 3-pass), weights staged per ks into smem[0:32K) ----
    f32x4 ga[8], ua[8];
    #pragma unroll
    for (int i = 0; i < 8; ++i) { ga[i] = (f32x4)0.f; ua[i] = (f32x4)0.f; }

    uint4* sB4 = (uint4*)smem;
    const unsigned short* sB = (const unsigned short*)smem;
    for (int ks = 0; ks < 8; ++ks) {
        #pragma unroll
        for (int i = 0; i < 2; ++i) {
            int idx = tid + i * 256;
            sB4[idx]        = ((const uint4*)WgH )[ks * 512 + idx];
            sB4[512 + idx]  = ((const uint4*)WgL )[ks * 512 + idx];
            sB4[1024 + idx] = ((const uint4*)Wu1H)[ks * 512 + idx];
            sB4[1536 + idx] = ((const uint4*)Wu1L)[ks * 512 + idx];
        }
        __syncthreads();
        #pragma unroll
        for (int nt = 0; nt < 8; ++nt) {
            size_t o = (size_t)(nt * 64 + lane) * 8;
            short8 bh = *(const short8*)(sB + o);
            short8 bl = *(const short8*)(sB + 4096 + o);
            ga[nt] = __builtin_amdgcn_mfma_f32_16x16x32_bf16(ah[ks], bh, ga[nt], 0, 0, 0);
            ga[nt] = __builtin_amdgcn_mfma_f32_16x16x32_bf16(al[ks], bh, ga[nt], 0, 0, 0);
            ga[nt] = __builtin_amdgcn_mfma_f32_16x16x32_bf16(ah[ks], bl, ga[nt], 0, 0, 0);
            short8 uh = *(const short8*)(sB + 8192 + o);
            short8 ul = *(const short8*)(sB + 12288 + o);
            ua[nt] = __builtin_amdgcn_mfma_f32_16x16x32_bf16(ah[ks], uh, ua[nt], 0, 0, 0);
            ua[nt] = __builtin_amdgcn_mfma_f32_16x16x32_bf16(al[ks], uh, ua[nt], 0, 0, 0);
            ua[nt] = __builtin_amdgcn_mfma_f32_16x16x32_bf16(ah[ks], ul, ua[nt], 0, 0, 0);
        }
        __syncthreads();   // all reads of this chunk complete before next stage / Hs overlay
    }

    // + deg * composed-bias terms
    #pragma unroll
    for (int nt = 0; nt < 8; ++nt) {
        int col = nt * 16 + arow;
        float bgc = bcg[col], buc = bcu[col];
        #pragma unroll
        for (int r = 0; r < 4; ++r) {
            ga[nt][r] = fmaf(degf[r], bgc, ga[nt][r]);
            ua[nt][r] = fmaf(degf[r], buc, ua[nt][r]);
        }
    }

    // relu + bias, hi/lo pack into wave-private Hs (overlays smem[0:32K))
    char* Hw = smem + wid * 8192;
    #pragma unroll
    for (int nt = 0; nt < 8; ++nt) {
        int col = nt * 16 + arow;
        float b1 = bu1[col];
        #pragma unroll
        for (int r = 0; r < 4; ++r) {
            int row = g4 * 4 + r;
            float u = fmaxf(ua[nt][r] + b1, 0.f);
            unsigned short h = f2bf(u);
            unsigned short l = f2bf(u - bf2f(h));
            unsigned int pk = (unsigned int)h | ((unsigned int)l << 16);
            *(unsigned int*)(Hw + row * 512 + ((col * 4) ^ ((row & 15) << 4))) = pk;
        }
    }

    // gate sigmoid
    #pragma unroll
    for (int nt = 0; nt < 8; ++nt) {
        int col = nt * 16 + arow;
        float b = bg[col];
        #pragma unroll
        for (int r = 0; r < 4; ++r)
            ga[nt][r] = 1.f / (1.f + expf(-(ga[nt][r] + b)));
    }
    __syncthreads();

    // ---- u2 GEMM (K=128, 3-pass), weights staged per ks into smem[32K:48K) ----
    uint4* sC4 = (uint4*)(smem + 32768);
    const unsigned short* sC = (const unsigned short*)(smem + 32768);
    f32x4 u2[8];
    #pragma unroll
    for (int i = 0; i < 8; ++i) u2[i] = (f32x4)0.f;
    for (int ks = 0; ks < 4; ++ks) {
        #pragma unroll
        for (int i = 0; i < 2; ++i) {
            int idx = tid + i * 256;
            sC4[idx]       = ((const uint4*)Wu2H)[ks * 512 + idx];
            sC4[512 + idx] = ((const uint4*)Wu2L)[ks * 512 + idx];
        }
        __syncthreads();
        int b0 = ks * 128 + g4 * 32;
        unsigned int q0[4], q1[4];
        *(uint4*)q0 = *(const uint4*)(Hw + arow * 512 + ( b0       ^ (arow << 4)));
        *(uint4*)q1 = *(const uint4*)(Hw + arow * 512 + ((b0 + 16) ^ (arow << 4)));
        short8 a2h, a2l;
        #pragma unroll
        for (int j = 0; j < 4; ++j) {
            a2h[j]     = (short)(q0[j] & 0xffff);
            a2l[j]     = (short)(q0[j] >> 16);
            a2h[4 + j] = (short)(q1[j] & 0xffff);
            a2l[4 + j] = (short)(q1[j] >> 16);
        }
        #pragma unroll
        for (int nt = 0; nt < 8; ++nt) {
            size_t o = (size_t)(nt * 64 + lane) * 8;
            short8 bh = *(const short8*)(sC + o);
            short8 bl = *(const short8*)(sC + 4096 + o);
            u2[nt] = __builtin_amdgcn_mfma_f32_16x16x32_bf16(a2h, bh, u2[nt], 0, 0, 0);
            u2[nt] = __builtin_amdgcn_mfma_f32_16x16x32_bf16(a2l, bh, u2[nt], 0, 0, 0);
            u2[nt] = __builtin_amdgcn_mfma_f32_16x16x32_bf16(a2h, bl, u2[nt], 0, 0, 0);
        }
        __syncthreads();
    }

    // ---- epilogue: gating + LayerNorm + store ----
    float s[4]  = {0.f, 0.f, 0.f, 0.f};
    float ss[4] = {0.f, 0.f, 0.f, 0.f};
    #pragma unroll
    for (int nt = 0; nt < 8; ++nt) {
        int col = nt * 16 + arow;
        float b2 = bu2[col];
        #pragma unroll
        for (int r = 0; r < 4; ++r) {
            int node = n0 + g4 * 4 + r;
            int nc = (node >= 0 && node < N) ? node : 0;
            float xv = x[(size_t)nc * 128 + col];
            float g  = ga[nt][r];
            float o  = g * (u2[nt][r] + b2) + (1.f - g) * xv;
            u2[nt][r] = o;
            s[r]  += o;
            ss[r] += o * o;
        }
    }
    #pragma unroll
    for (int off = 8; off >= 1; off >>= 1) {
        #pragma unroll
        for (int r = 0; r < 4; ++r) {
            s[r]  += __shfl_xor(s[r],  off);
            ss[r] += __shfl_xor(ss[r], off);
        }
    }
    float mu[4], rstd[4];
    #pragma unroll
    for (int r = 0; r < 4; ++r) {
        mu[r] = s[r] * (1.f / 128.f);
        float var = ss[r] * (1.f / 128.f) - mu[r] * mu[r];
        rstd[r] = rsqrtf(var + 1e-5f);
    }
    #pragma unroll
    for (int nt = 0; nt < 8; ++nt) {
        int col = nt * 16 + arow;
        float gm = gamma[col], bt = beta[col];
        #pragma unroll
        for (int r = 0; r < 4; ++r) {
            int node = n0 + g4 * 4 + r;
            if (node >= 0 && node < N)
                out[(size_t)node * 128 + col] = (u2[nt][r] - mu[r]) * rstd[r] * gm + bt;
        }
    }
}

extern "C" void kernel_launch(void* const* d_in, const int* in_sizes, int n_in,
                              void* d_out, int out_size, void* d_ws, size_t ws_size,
                              hipStream_t stream)
{
    const float* x    = (const float*)d_in[0];
    const int*   ei   = (const int*)  d_in[1];
    const float* ea   = (const float*)d_in[2];
    const float* Wm1  = (const float*)d_in[3];
    const float* bm1  = (const float*)d_in[4];
    const float* Wm2  = (const float*)d_in[5];
    const float* bm2  = (const float*)d_in[6];
    const float* Wg   = (const float*)d_in[7];
    const float* bg   = (const float*)d_in[8];
    const float* Wu1  = (const float*)d_in[9];
    const float* bu1  = (const float*)d_in[10];
    const float* Wu2  = (const float*)d_in[11];
    const float* bu2  = (const float*)d_in[12];
    const float* gmma = (const float*)d_in[13];
    const float* beta = (const float*)d_in[14];
    float* out = (float*)d_out;

    const int N = in_sizes[0] / HID;
    const int E = in_sizes[1] / 2;

    // workspace carve-up
    unsigned short* S1b  = (unsigned short*)d_ws;            // N*128 bf16
    unsigned short* Tb   = S1b + (size_t)N * HID;            // N*128 bf16
    float*          HS   = (float*)(Tb + (size_t)N * HID);   // N*128 f32
    unsigned short* W1f  = (unsigned short*)(HS + (size_t)N * HID); // 32768
    unsigned short* WgH  = W1f + 32768;
    unsigned short* WgL  = WgH + 32768;
    unsigned short* Wu1H = WgL + 32768;
    unsigned short* Wu1L = Wu1H + 32768;
    unsigned short* Wu2H = Wu1L + 32768;
    unsigned short* Wu2L = Wu2H + 16384;
    float*          bcg  = (float*)(Wu2L + 16384);           // 128
    float*          bcu  = bcg + 128;                        // 128
    unsigned*       cnt  = (unsigned*)(bcu + 128);           // N
    unsigned*       cur  = cnt + N;                          // N
    uint4*          rec  = (uint4*)(cur + N);
    rec = (uint4*)(((size_t)rec + 15) & ~(size_t)15);
    size_t need_sort = (size_t)((char*)(rec + E) - (char*)d_ws);
    const bool tierA = (ws_size >= need_sort);

    // weights prep
    prep_w<<<dim3(16), dim3(256), 0, stream>>>(Wm1, W1f, 8);
    prep_split_comp<<<dim3(128), dim3(256), 0, stream>>>(Wg,  Wm2, bm2, WgH,  WgL,  bcg);
    prep_split_comp<<<dim3(128), dim3(256), 0, stream>>>(Wu1, Wm2, bm2, Wu1H, Wu1L, bcu);
    prep_w_split<<<dim3(8), dim3(256), 0, stream>>>(Wu2, Wu2H, Wu2L, 4);

    // dense per-node S1/T
    s1t_gemm<<<dim3((N + 63) / 64), dim3(256), 0, stream>>>(x, W1f, S1b, Tb, N);

    // degree histogram
    hipMemsetAsync(cnt, 0, (size_t)N * sizeof(unsigned), stream);
    hist_k<<<dim3((E + 255) / 256), dim3(256), 0, stream>>>(ei, cnt, E);

    if (tierA) {
        scan_k<<<dim3(1), dim3(1024), 0, stream>>>(cnt, cur, N);
        scatter_k<<<dim3((E + 255) / 256), dim3(256), 0, stream>>>(ei, ea, cur, rec, E);
        csr_edge_k<<<dim3(2048), dim3(256), 0, stream>>>(
            S1b, Tb, rec, cnt, cur, Wm1 + 256 * HID, bm1, HS, N);
    } else {
        hipMemsetAsync(HS, 0, (size_t)N * HID * sizeof(float), stream);
        atomic_edge_k<<<dim3(2048), dim3(256), 0, stream>>>(
            S1b, Tb, ei, ea, Wm1 + 256 * HID, bm1, HS, E);
    }

    node_mfma<<<dim3((N + 63) / 64), dim3(256), 0, stream>>>(
        x, HS, cnt, bcg, bcu,
        WgH, WgL, Wu1H, Wu1L, Wu2H, Wu2L,
        bg, bu1, bu2, gmma, beta, out, N);
}

// Round 17
// 241.355 us; speedup vs baseline: 1.2405x; 1.0498x over previous
//
#include <hip/hip_runtime.h>
#include <hip/hip_bf16.h>

#define HID 128

typedef __attribute__((ext_vector_type(8))) short short8;
typedef __attribute__((ext_vector_type(4))) float f32x4;

__device__ __forceinline__ unsigned short f2bf(float f) {
    unsigned int u = __builtin_bit_cast(unsigned int, f);
    u += 0x7FFFu + ((u >> 16) & 1u);
    return (unsigned short)(u >> 16);
}
__device__ __forceinline__ float bf2f(unsigned short h) {
    unsigned int u = ((unsigned int)h) << 16;
    return __builtin_bit_cast(float, u);
}

// ---------------- prep: W[k][128] f32 -> fragment order Wf[ks][nt][lane][j] bf16 ----------------
__global__ void prep_w(const float* __restrict__ W, unsigned short* __restrict__ Wf, int nks) {
    int t = blockIdx.x * 256 + threadIdx.x;
    if (t >= nks * 8 * 64) return;
    int lane = t & 63, nt = (t >> 6) & 7, ks = t >> 9;
    int kb  = ks * 32 + ((lane >> 4) << 3);
    int col = (nt << 4) + (lane & 15);
    union { unsigned short u[8]; uint4 q; } p;
    #pragma unroll
    for (int j = 0; j < 8; ++j) p.u[j] = f2bf(W[(size_t)(kb + j) * 128 + col]);
    *(uint4*)(Wf + (size_t)t * 8) = p.q;
}

// ---------------- fused compose+stack -> bf16 frags + composed bias (one elem/thread) ----------
__global__ void prep_comp(const float* __restrict__ Wtop,  // [256][128]
                          const float* __restrict__ Wm2,   // [128][128]
                          const float* __restrict__ b2,    // [128]
                          unsigned short* __restrict__ Wh,
                          float* __restrict__ bc)
{
    int t = blockIdx.x * 256 + threadIdx.x;
    if (t < 32768) {
        int j = t & 7, lane = (t >> 3) & 63, nt = (t >> 9) & 7, ks = t >> 12;
        int r   = ks * 32 + ((lane >> 4) << 3) + j;
        int col = (nt << 4) + (lane & 15);
        float w;
        if (r < 128) {
            w = Wtop[(size_t)r * 128 + col];
        } else {
            const float* a = Wm2 + (size_t)(r - 128) * 128;
            float s = 0.f;
            for (int k = 0; k < 128; ++k)
                s = fmaf(a[k], Wtop[(size_t)(128 + k) * 128 + col], s);
            w = s;
        }
        Wh[t] = f2bf(w);
    }
    if (blockIdx.x == 0 && threadIdx.x < 128) {
        int jj = threadIdx.x;
        float s = 0.f;
        for (int k = 0; k < 128; ++k)
            s = fmaf(b2[k], Wtop[(size_t)(128 + k) * 128 + jj], s);
        bc[jj] = s;
    }
}

// ---------------- counting sort by dst -> fused 16B edge records ----------------
__global__ void hist_k(const int* __restrict__ ei, unsigned* __restrict__ cnt, int E) {
    int e = blockIdx.x * 256 + threadIdx.x;
    if (e < E) atomicAdd(&cnt[ei[E + e]], 1u);
}

// single-block scan, x4 vectorized
__global__ void scan_k(const unsigned* __restrict__ cnt, unsigned* __restrict__ cur, int n) {
    __shared__ unsigned wsum[16];
    int tid = threadIdx.x, lane = tid & 63, w = tid >> 6;
    unsigned carry = 0;
    for (int base = 0; base < n; base += 4096) {
        int i = base + tid * 4;
        unsigned v0 = 0, v1 = 0, v2 = 0, v3 = 0;
        if (i + 3 < n) {
            uint4 q = *(const uint4*)(cnt + i);
            v0 = q.x; v1 = q.y; v2 = q.z; v3 = q.w;
        } else {
            if (i < n)     v0 = cnt[i];
            if (i + 1 < n) v1 = cnt[i + 1];
            if (i + 2 < n) v2 = cnt[i + 2];
            if (i + 3 < n) v3 = cnt[i + 3];
        }
        unsigned t0 = v0, t1 = t0 + v1, t2 = t1 + v2, t3 = t2 + v3;
        unsigned s = t3;
        #pragma unroll
        for (int off = 1; off < 64; off <<= 1) {
            unsigned t = __shfl_up(s, off);
            if (lane >= off) s += t;
        }
        if (lane == 63) wsum[w] = s;
        __syncthreads();
        if (tid < 16) {
            unsigned t = wsum[tid];
            #pragma unroll
            for (int off = 1; off < 16; off <<= 1) {
                unsigned u = __shfl_up(t, off);
                if (tid >= off) t += u;
            }
            wsum[tid] = t;
        }
        __syncthreads();
        unsigned woff = (w == 0) ? 0u : wsum[w - 1];
        unsigned excl = carry + woff + (s - t3);
        if (i < n)     cur[i]     = excl;
        if (i + 1 < n) cur[i + 1] = excl + t0;
        if (i + 2 < n) cur[i + 2] = excl + t1;
        if (i + 3 < n) cur[i + 3] = excl + t2;
        unsigned tot = wsum[15];
        __syncthreads();
        carry += tot;
    }
}

__global__ void scatter_k(const int* __restrict__ ei, const float* __restrict__ ea,
                          unsigned* __restrict__ cur, uint4* __restrict__ rec, int E) {
    int e = blockIdx.x * 256 + threadIdx.x;
    if (e >= E) return;
    int d = ei[E + e];
    unsigned pos = atomicAdd(&cur[d], 1u);
    uint4 r;
    r.x = (unsigned)ei[e];
    r.y = __builtin_bit_cast(unsigned, ea[(size_t)e * 3 + 0]);
    r.z = __builtin_bit_cast(unsigned, ea[(size_t)e * 3 + 1]);
    r.w = __builtin_bit_cast(unsigned, ea[(size_t)e * 3 + 2]);
    rec[pos] = r;
}

// ---------------- S1 = x@W1[:128], T = x@W1[128:256], B from LDS ----------------
__global__ __launch_bounds__(256, 2)
void s1t_gemm(const float* __restrict__ x, const unsigned short* __restrict__ W1f,
              unsigned short* __restrict__ S1b, unsigned short* __restrict__ Tb, int N)
{
    __shared__ alignas(16) unsigned short sW[32768];
    const int tid  = threadIdx.x;
    for (int i = tid; i < 4096; i += 256)
        ((uint4*)sW)[i] = ((const uint4*)W1f)[i];
    __syncthreads();

    const int lane = tid & 63;
    const int wid  = tid >> 6;
    const int n0   = (blockIdx.x * 4 + wid) * 16;
    if (n0 >= N) return;
    const int arow = lane & 15;
    const int g4   = lane >> 4;

    int nr = n0 + arow; if (nr >= N) nr = N - 1;
    const float* px = x + (size_t)nr * 128 + g4 * 8;

    short8 af[4];
    #pragma unroll
    for (int ks = 0; ks < 4; ++ks) {
        float4 v0 = *(const float4*)(px + ks * 32);
        float4 v1 = *(const float4*)(px + ks * 32 + 4);
        float v[8] = { v0.x, v0.y, v0.z, v0.w, v1.x, v1.y, v1.z, v1.w };
        #pragma unroll
        for (int j = 0; j < 8; ++j) af[ks][j] = (short)f2bf(v[j]);
    }

    f32x4 s1[8], tt[8];
    #pragma unroll
    for (int i = 0; i < 8; ++i) { s1[i] = (f32x4)0.f; tt[i] = (f32x4)0.f; }
    #pragma unroll
    for (int ks = 0; ks < 4; ++ks) {
        #pragma unroll
        for (int nt = 0; nt < 8; ++nt) {
            short8 b1 = *(const short8*)(sW + (size_t)((ks * 8 + nt) * 64 + lane) * 8);
            short8 b2 = *(const short8*)(sW + (size_t)(((ks + 4) * 8 + nt) * 64 + lane) * 8);
            s1[nt] = __builtin_amdgcn_mfma_f32_16x16x32_bf16(af[ks], b1, s1[nt], 0, 0, 0);
            tt[nt] = __builtin_amdgcn_mfma_f32_16x16x32_bf16(af[ks], b2, tt[nt], 0, 0, 0);
        }
    }
    #pragma unroll
    for (int nt = 0; nt < 8; ++nt) {
        int col = nt * 16 + arow;
        #pragma unroll
        for (int r = 0; r < 4; ++r) {
            int node = n0 + g4 * 4 + r;
            if (node < N) {
                S1b[(size_t)node * 128 + col] = f2bf(s1[nt][r]);
                Tb [(size_t)node * 128 + col] = f2bf(tt[nt][r]);
            }
        }
    }
}

// ---------------- CSR edge kernel: depth-2 pipelined gather-reduce, zero atomics ----------------
__global__ __launch_bounds__(256, 8)
void csr_edge_k(const unsigned short* __restrict__ S1b, const unsigned short* __restrict__ Tb,
                const uint4* __restrict__ rec,
                const unsigned* __restrict__ cnt, const unsigned* __restrict__ cur,
                const float* __restrict__ W1tail, const float* __restrict__ bm1,
                float* __restrict__ HS, int N)
{
    const int lane = threadIdx.x & 63;
    const int wid  = threadIdx.x >> 6;
    const int gw   = blockIdx.x * 4 + wid;
    const int stride = gridDim.x * 4;
    const int c2 = lane * 2;

    const float w00 = W1tail[c2],       w01 = W1tail[c2 + 1];
    const float w10 = W1tail[128 + c2], w11 = W1tail[128 + c2 + 1];
    const float w20 = W1tail[256 + c2], w21 = W1tail[256 + c2 + 1];
    const float b0  = bm1[c2],          b1v = bm1[c2 + 1];

    for (int d = gw; d < N; d += stride) {
        int e1 = (int)cur[d];
        int c  = (int)cnt[d];
        int e0 = e1 - c;
        unsigned tv = *(const unsigned*)(Tb + (size_t)d * 128 + c2);
        float t0 = bf2f((unsigned short)(tv & 0xffff)) + b0;
        float t1 = bf2f((unsigned short)(tv >> 16))    + b1v;
        float a0 = 0.f, a1 = 0.f;
        if (c > 0) {
            uint4 r0 = rec[e0];
            uint4 r1 = (c > 1) ? rec[e0 + 1] : make_uint4(0u, 0u, 0u, 0u);
            unsigned sv0 = *(const unsigned*)(S1b + (size_t)r0.x * 128 + c2);
            for (int e = e0; e < e1; ++e) {
                uint4 r2 = (e + 2 < e1) ? rec[e + 2] : make_uint4(0u, 0u, 0u, 0u);
                unsigned sv1 = (e + 1 < e1)
                    ? *(const unsigned*)(S1b + (size_t)r1.x * 128 + c2) : 0u;
                float x0 = __builtin_bit_cast(float, r0.y);
                float x1 = __builtin_bit_cast(float, r0.z);
                float x2 = __builtin_bit_cast(float, r0.w);
                float h0 = bf2f((unsigned short)(sv0 & 0xffff)) + t0;
                float h1 = bf2f((unsigned short)(sv0 >> 16))    + t1;
                h0 = fmaf(x0, w00, h0); h0 = fmaf(x1, w10, h0); h0 = fmaf(x2, w20, h0);
                h1 = fmaf(x0, w01, h1); h1 = fmaf(x1, w11, h1); h1 = fmaf(x2, w21, h1);
                a0 += fmaxf(h0, 0.f);
                a1 += fmaxf(h1, 0.f);
                r0 = r1; r1 = r2; sv0 = sv1;
            }
        }
        float2 o; o.x = a0; o.y = a1;
        *(float2*)(HS + (size_t)d * 128 + c2) = o;
    }
}

// tier-B fallback: per-edge atomics from raw inputs (HS pre-zeroed)
__global__ __launch_bounds__(256, 8)
void atomic_edge_k(const unsigned short* __restrict__ S1b, const unsigned short* __restrict__ Tb,
                   const int* __restrict__ ei, const float* __restrict__ ea,
                   const float* __restrict__ W1tail, const float* __restrict__ bm1,
                   float* __restrict__ HS, int E)
{
    const int lane = threadIdx.x & 63;
    const int wid  = threadIdx.x >> 6;
    const int gw   = blockIdx.x * 4 + wid;
    const int stride = gridDim.x * 4;
    const int c2 = lane * 2;

    const float w00 = W1tail[c2],       w01 = W1tail[c2 + 1];
    const float w10 = W1tail[128 + c2], w11 = W1tail[128 + c2 + 1];
    const float w20 = W1tail[256 + c2], w21 = W1tail[256 + c2 + 1];
    const float b0  = bm1[c2],          b1v = bm1[c2 + 1];

    for (int e = gw; e < E; e += stride) {
        int s = ei[e], d = ei[E + e];
        float x0 = ea[(size_t)e * 3 + 0];
        float x1 = ea[(size_t)e * 3 + 1];
        float x2 = ea[(size_t)e * 3 + 2];
        unsigned tv = *(const unsigned*)(Tb + (size_t)d * 128 + c2);
        unsigned sv = *(const unsigned*)(S1b + (size_t)s * 128 + c2);
        float h0 = bf2f((unsigned short)(sv & 0xffff)) + bf2f((unsigned short)(tv & 0xffff)) + b0;
        float h1 = bf2f((unsigned short)(sv >> 16))    + bf2f((unsigned short)(tv >> 16))    + b1v;
        h0 = fmaf(x0, w00, h0); h0 = fmaf(x1, w10, h0); h0 = fmaf(x2, w20, h0);
        h1 = fmaf(x0, w01, h1); h1 = fmaf(x1, w11, h1); h1 = fmaf(x2, w21, h1);
        unsafeAtomicAdd(HS + (size_t)d * 128 + c2,     fmaxf(h0, 0.f));
        unsafeAtomicAdd(HS + (size_t)d * 128 + c2 + 1, fmaxf(h1, 0.f));
    }
}

// ---------------- Node kernel: 2-pass (A hi/lo x B hi), 16KB weight chunks ----------------
__global__ __launch_bounds__(256, 2)
void node_mfma(const float* __restrict__ x,
               const float* __restrict__ HS,
               const unsigned* __restrict__ cnt,
               const float* __restrict__ bcg, const float* __restrict__ bcu,
               const unsigned short* __restrict__ WgH,
               const unsigned short* __restrict__ Wu1H,
               const unsigned short* __restrict__ Wu2H,
               const float* __restrict__ bg, const float* __restrict__ bu1,
               const float* __restrict__ bu2,
               const float* __restrict__ gamma, const float* __restrict__ beta,
               float* __restrict__ out, int N)
{
    // [0,16K): weight chunks (gate 8K + u1 8K per ks; later u2 8K per ks)
    // [16K,48K): Hs u1-transpose (4 waves x 8 KB)
    __shared__ alignas(16) char smem[49152];

    const int tid  = threadIdx.x;
    const int lane = tid & 63;
    const int wid  = tid >> 6;
    const int n0   = (blockIdx.x * 4 + wid) * 16;
    // NO early return: block barriers are cooperative.

    const int arow = lane & 15;
    const int g4   = lane >> 4;

    int nr = n0 + arow; if (nr >= N) nr = N - 1;
    if (nr < 0) nr = 0;
    const float* px = x  + (size_t)nr * 128 + g4 * 8;
    const float* pa = HS + (size_t)nr * 128 + g4 * 8;

    short8 ah[8], al[8];
    #pragma unroll
    for (int ks = 0; ks < 8; ++ks) {
        const float* p = (ks < 4) ? (px + ks * 32) : (pa + (ks - 4) * 32);
        float4 v0 = *(const float4*)p;
        float4 v1 = *(const float4*)(p + 4);
        float v[8] = { v0.x, v0.y, v0.z, v0.w, v1.x, v1.y, v1.z, v1.w };
        #pragma unroll
        for (int j = 0; j < 8; ++j) {
            unsigned short h = f2bf(v[j]);
            ah[ks][j] = (short)h;
            al[ks][j] = (short)f2bf(v[j] - bf2f(h));
        }
    }

    float degf[4];
    #pragma unroll
    for (int r = 0; r < 4; ++r) {
        int node = n0 + g4 * 4 + r;
        degf[r] = (node >= 0 && node < N) ? (float)cnt[node] : 0.f;
    }

    // ---- gate + u1 GEMMs (K=256, 2-pass: ah@bh + al@bh) ----
    f32x4 ga[8], ua[8];
    #pragma unroll
    for (int i = 0; i < 8; ++i) { ga[i] = (f32x4)0.f; ua[i] = (f32x4)0.f; }

    uint4* sB4 = (uint4*)smem;
    const unsigned short* sB = (const unsigned short*)smem;
    for (int ks = 0; ks < 8; ++ks) {
        #pragma unroll
        for (int i = 0; i < 2; ++i) {
            int idx = tid + i * 256;
            sB4[idx]       = ((const uint4*)WgH )[ks * 512 + idx];
            sB4[512 + idx] = ((const uint4*)Wu1H)[ks * 512 + idx];
        }
        __syncthreads();
        #pragma unroll
        for (int nt = 0; nt < 8; ++nt) {
            size_t o = (size_t)(nt * 64 + lane) * 8;
            short8 bh = *(const short8*)(sB + o);
            short8 uh = *(const short8*)(sB + 4096 + o);
            ga[nt] = __builtin_amdgcn_mfma_f32_16x16x32_bf16(ah[ks], bh, ga[nt], 0, 0, 0);
            ga[nt] = __builtin_amdgcn_mfma_f32_16x16x32_bf16(al[ks], bh, ga[nt], 0, 0, 0);
            ua[nt] = __builtin_amdgcn_mfma_f32_16x16x32_bf16(ah[ks], uh, ua[nt], 0, 0, 0);
            ua[nt] = __builtin_amdgcn_mfma_f32_16x16x32_bf16(al[ks], uh, ua[nt], 0, 0, 0);
        }
        __syncthreads();
    }

    // + deg * composed-bias terms
    #pragma unroll
    for (int nt = 0; nt < 8; ++nt) {
        int col = nt * 16 + arow;
        float bgc = bcg[col], buc = bcu[col];
        #pragma unroll
        for (int r = 0; r < 4; ++r) {
            ga[nt][r] = fmaf(degf[r], bgc, ga[nt][r]);
            ua[nt][r] = fmaf(degf[r], buc, ua[nt][r]);
        }
    }

    // relu + bias, hi/lo pack into wave-private Hs at [16K,48K)
    char* Hw = smem + 16384 + wid * 8192;
    #pragma unroll
    for (int nt = 0; nt < 8; ++nt) {
        int col = nt * 16 + arow;
        float b1 = bu1[col];
        #pragma unroll
        for (int r = 0; r < 4; ++r) {
            int row = g4 * 4 + r;
            float u = fmaxf(ua[nt][r] + b1, 0.f);
            unsigned short h = f2bf(u);
            unsigned short l = f2bf(u - bf2f(h));
            unsigned int pk = (unsigned int)h | ((unsigned int)l << 16);
            *(unsigned int*)(Hw + row * 512 + ((col * 4) ^ ((row & 15) << 4))) = pk;
        }
    }

    // gate sigmoid
    #pragma unroll
    for (int nt = 0; nt < 8; ++nt) {
        int col = nt * 16 + arow;
        float b = bg[col];
        #pragma unroll
        for (int r = 0; r < 4; ++r)
            ga[nt][r] = 1.f / (1.f + expf(-(ga[nt][r] + b)));
    }
    __syncthreads();

    // ---- u2 GEMM (K=128, 2-pass), 8KB weight chunk per ks ----
    f32x4 u2[8];
    #pragma unroll
    for (int i = 0; i < 8; ++i) u2[i] = (f32x4)0.f;
    for (int ks = 0; ks < 4; ++ks) {
        {
            int idx = tid;
            sB4[idx] = ((const uint4*)Wu2H)[ks * 512 + idx];
            sB4[256 + idx] = ((const uint4*)Wu2H)[ks * 512 + 256 + idx];
        }
        __syncthreads();
        int b0 = ks * 128 + g4 * 32;
        unsigned int q0[4], q1[4];
        *(uint4*)q0 = *(const uint4*)(Hw + arow * 512 + ( b0       ^ (arow << 4)));
        *(uint4*)q1 = *(const uint4*)(Hw + arow * 512 + ((b0 + 16) ^ (arow << 4)));
        short8 a2h, a2l;
        #pragma unroll
        for (int j = 0; j < 4; ++j) {
            a2h[j]     = (short)(q0[j] & 0xffff);
            a2l[j]     = (short)(q0[j] >> 16);
            a2h[4 + j] = (short)(q1[j] & 0xffff);
            a2l[4 + j] = (short)(q1[j] >> 16);
        }
        #pragma unroll
        for (int nt = 0; nt < 8; ++nt) {
            size_t o = (size_t)(nt * 64 + lane) * 8;
            short8 bh = *(const short8*)(sB + o);
            u2[nt] = __builtin_amdgcn_mfma_f32_16x16x32_bf16(a2h, bh, u2[nt], 0, 0, 0);
            u2[nt] = __builtin_amdgcn_mfma_f32_16x16x32_bf16(a2l, bh, u2[nt], 0, 0, 0);
        }
        __syncthreads();
    }

    // ---- epilogue: gating + LayerNorm + store ----
    float s[4]  = {0.f, 0.f, 0.f, 0.f};
    float ss[4] = {0.f, 0.f, 0.f, 0.f};
    #pragma unroll
    for (int nt = 0; nt < 8; ++nt) {
        int col = nt * 16 + arow;
        float b2 = bu2[col];
        #pragma unroll
        for (int r = 0; r < 4; ++r) {
            int node = n0 + g4 * 4 + r;
            int nc = (node >= 0 && node < N) ? node : 0;
            float xv = x[(size_t)nc * 128 + col];
            float g  = ga[nt][r];
            float o  = g * (u2[nt][r] + b2) + (1.f - g) * xv;
            u2[nt][r] = o;
            s[r]  += o;
            ss[r] += o * o;
        }
    }
    #pragma unroll
    for (int off = 8; off >= 1; off >>= 1) {
        #pragma unroll
        for (int r = 0; r < 4; ++r) {
            s[r]  += __shfl_xor(s[r],  off);
            ss[r] += __shfl_xor(ss[r], off);
        }
    }
    float mu[4], rstd[4];
    #pragma unroll
    for (int r = 0; r < 4; ++r) {
        mu[r] = s[r] * (1.f / 128.f);
        float var = ss[r] * (1.f / 128.f) - mu[r] * mu[r];
        rstd[r] = rsqrtf(var + 1e-5f);
    }
    #pragma unroll
    for (int nt = 0; nt < 8; ++nt) {
        int col = nt * 16 + arow;
        float gm = gamma[col], bt = beta[col];
        #pragma unroll
        for (int r = 0; r < 4; ++r) {
            int node = n0 + g4 * 4 + r;
            if (node >= 0 && node < N)
                out[(size_t)node * 128 + col] = (u2[nt][r] - mu[r]) * rstd[r] * gm + bt;
        }
    }
}

extern "C" void kernel_launch(void* const* d_in, const int* in_sizes, int n_in,
                              void* d_out, int out_size, void* d_ws, size_t ws_size,
                              hipStream_t stream)
{
    const float* x    = (const float*)d_in[0];
    const int*   ei   = (const int*)  d_in[1];
    const float* ea   = (const float*)d_in[2];
    const float* Wm1  = (const float*)d_in[3];
    const float* bm1  = (const float*)d_in[4];
    const float* Wm2  = (const float*)d_in[5];
    const float* bm2  = (const float*)d_in[6];
    const float* Wg   = (const float*)d_in[7];
    const float* bg   = (const float*)d_in[8];
    const float* Wu1  = (const float*)d_in[9];
    const float* bu1  = (const float*)d_in[10];
    const float* Wu2  = (const float*)d_in[11];
    const float* bu2  = (const float*)d_in[12];
    const float* gmma = (const float*)d_in[13];
    const float* beta = (const float*)d_in[14];
    float* out = (float*)d_out;

    const int N = in_sizes[0] / HID;
    const int E = in_sizes[1] / 2;

    // workspace carve-up
    unsigned short* S1b  = (unsigned short*)d_ws;            // N*128 bf16
    unsigned short* Tb   = S1b + (size_t)N * HID;            // N*128 bf16
    float*          HS   = (float*)(Tb + (size_t)N * HID);   // N*128 f32
    unsigned short* W1f  = (unsigned short*)(HS + (size_t)N * HID); // 32768
    unsigned short* WgH  = W1f + 32768;
    unsigned short* Wu1H = WgH + 32768;
    unsigned short* Wu2H = Wu1H + 32768;
    float*          bcg  = (float*)(Wu2H + 16384);           // 128
    float*          bcu  = bcg + 128;                        // 128
    unsigned*       cnt  = (unsigned*)(bcu + 128);           // N
    unsigned*       cur  = cnt + N;                          // N
    uint4*          rec  = (uint4*)(cur + N);
    rec = (uint4*)(((size_t)rec + 15) & ~(size_t)15);
    size_t need_sort = (size_t)((char*)(rec + E) - (char*)d_ws);
    const bool tierA = (ws_size >= need_sort);

    // weights prep
    prep_w<<<dim3(16), dim3(256), 0, stream>>>(Wm1, W1f, 8);
    prep_comp<<<dim3(128), dim3(256), 0, stream>>>(Wg,  Wm2, bm2, WgH,  bcg);
    prep_comp<<<dim3(128), dim3(256), 0, stream>>>(Wu1, Wm2, bm2, Wu1H, bcu);
    prep_w<<<dim3(8), dim3(256), 0, stream>>>(Wu2, Wu2H, 4);

    // dense per-node S1/T
    s1t_gemm<<<dim3((N + 63) / 64), dim3(256), 0, stream>>>(x, W1f, S1b, Tb, N);

    // degree histogram
    hipMemsetAsync(cnt, 0, (size_t)N * sizeof(unsigned), stream);
    hist_k<<<dim3((E + 255) / 256), dim3(256), 0, stream>>>(ei, cnt, E);

    if (tierA) {
        scan_k<<<dim3(1), dim3(1024), 0, stream>>>(cnt, cur, N);
        scatter_k<<<dim3((E + 255) / 256), dim3(256), 0, stream>>>(ei, ea, cur, rec, E);
        csr_edge_k<<<dim3(2048), dim3(256), 0, stream>>>(
            S1b, Tb, rec, cnt, cur, Wm1 + 256 * HID, bm1, HS, N);
    } else {
        hipMemsetAsync(HS, 0, (size_t)N * HID * sizeof(float), stream);
        atomic_edge_k<<<dim3(2048), dim3(256), 0, stream>>>(
            S1b, Tb, ei, ea, Wm1 + 256 * HID, bm1, HS, E);
    }

    node_mfma<<<dim3((N + 63) / 64), dim3(256), 0, stream>>>(
        x, HS, cnt, bcg, bcu,
        WgH, Wu1H, Wu2H,
        bg, bu1, bu2, gmma, beta, out, N);
}

// Round 18
// 228.591 us; speedup vs baseline: 1.3097x; 1.0558x over previous
//
#include <hip/hip_runtime.h>
#include <hip/hip_bf16.h>

#define HID 128

typedef __attribute__((ext_vector_type(8))) short short8;
typedef __attribute__((ext_vector_type(4))) float f32x4;

__device__ __forceinline__ unsigned short f2bf(float f) {
    unsigned int u = __builtin_bit_cast(unsigned int, f);
    u += 0x7FFFu + ((u >> 16) & 1u);
    return (unsigned short)(u >> 16);
}
__device__ __forceinline__ float bf2f(unsigned short h) {
    unsigned int u = ((unsigned int)h) << 16;
    return __builtin_bit_cast(float, u);
}

// ---------------- fused prep: W1f | comp(Wg) | comp(Wu1) | Wu2 frags | zero cnt ----------------
// block ranges: [0,16) W1f, [16,144) compWg, [144,272) compWu1, [272,280) Wu2, [280,329) zero cnt
__global__ void prep_all(const float* __restrict__ Wm1,
                         const float* __restrict__ Wg,  const float* __restrict__ Wu1,
                         const float* __restrict__ Wm2, const float* __restrict__ bm2,
                         const float* __restrict__ Wu2,
                         unsigned short* __restrict__ W1f,
                         unsigned short* __restrict__ WgH,  float* __restrict__ bcg,
                         unsigned short* __restrict__ Wu1H, float* __restrict__ bcu,
                         unsigned short* __restrict__ Wu2H,
                         unsigned* __restrict__ cnt, int N)
{
    int b = blockIdx.x;
    if (b < 16) {
        int t = b * 256 + threadIdx.x;
        if (t < 4096) {
            int lane = t & 63, nt = (t >> 6) & 7, ks = t >> 9;
            int kb  = ks * 32 + ((lane >> 4) << 3);
            int col = (nt << 4) + (lane & 15);
            union { unsigned short u[8]; uint4 q; } p;
            #pragma unroll
            for (int j = 0; j < 8; ++j) p.u[j] = f2bf(Wm1[(size_t)(kb + j) * 128 + col]);
            *(uint4*)(W1f + (size_t)t * 8) = p.q;
        }
    } else if (b < 272) {
        const bool isG = (b < 144);
        const float* Wtop = isG ? Wg : Wu1;
        unsigned short* Wh = isG ? WgH : Wu1H;
        float* bc = isG ? bcg : bcu;
        int lb = b - (isG ? 16 : 144);
        int t = lb * 256 + threadIdx.x;
        if (t < 32768) {
            int j = t & 7, lane = (t >> 3) & 63, nt = (t >> 9) & 7, ks = t >> 12;
            int r   = ks * 32 + ((lane >> 4) << 3) + j;
            int col = (nt << 4) + (lane & 15);
            float w;
            if (r < 128) {
                w = Wtop[(size_t)r * 128 + col];
            } else {
                const float* a = Wm2 + (size_t)(r - 128) * 128;
                float s = 0.f;
                for (int k = 0; k < 128; ++k)
                    s = fmaf(a[k], Wtop[(size_t)(128 + k) * 128 + col], s);
                w = s;
            }
            Wh[t] = f2bf(w);
        }
        if (lb == 0 && threadIdx.x < 128) {
            int jj = threadIdx.x;
            float s = 0.f;
            for (int k = 0; k < 128; ++k)
                s = fmaf(bm2[k], Wtop[(size_t)(128 + k) * 128 + jj], s);
            bc[jj] = s;
        }
    } else if (b < 280) {
        int t = (b - 272) * 256 + threadIdx.x;
        if (t < 2048) {
            int lane = t & 63, nt = (t >> 6) & 7, ks = t >> 9;
            int kb  = ks * 32 + ((lane >> 4) << 3);
            int col = (nt << 4) + (lane & 15);
            union { unsigned short u[8]; uint4 q; } p;
            #pragma unroll
            for (int j = 0; j < 8; ++j) p.u[j] = f2bf(Wu2[(size_t)(kb + j) * 128 + col]);
            *(uint4*)(Wu2H + (size_t)t * 8) = p.q;
        }
    } else {
        int t = (b - 280) * 256 + threadIdx.x;
        int i = t * 4;
        if (i + 3 < N) {
            *(uint4*)(cnt + i) = make_uint4(0u, 0u, 0u, 0u);
        } else {
            for (int k = 0; k < 4 && i + k < N; ++k) cnt[i + k] = 0u;
        }
    }
}

// ---------------- counting sort by dst -> fused 16B edge records ----------------
__global__ void hist_k(const int* __restrict__ ei, unsigned* __restrict__ cnt, int E) {
    int e = blockIdx.x * 256 + threadIdx.x;
    if (e < E) atomicAdd(&cnt[ei[E + e]], 1u);
}

__global__ void scan_k(const unsigned* __restrict__ cnt, unsigned* __restrict__ cur, int n) {
    __shared__ unsigned wsum[16];
    int tid = threadIdx.x, lane = tid & 63, w = tid >> 6;
    unsigned carry = 0;
    for (int base = 0; base < n; base += 4096) {
        int i = base + tid * 4;
        unsigned v0 = 0, v1 = 0, v2 = 0, v3 = 0;
        if (i + 3 < n) {
            uint4 q = *(const uint4*)(cnt + i);
            v0 = q.x; v1 = q.y; v2 = q.z; v3 = q.w;
        } else {
            if (i < n)     v0 = cnt[i];
            if (i + 1 < n) v1 = cnt[i + 1];
            if (i + 2 < n) v2 = cnt[i + 2];
            if (i + 3 < n) v3 = cnt[i + 3];
        }
        unsigned t0 = v0, t1 = t0 + v1, t2 = t1 + v2, t3 = t2 + v3;
        unsigned s = t3;
        #pragma unroll
        for (int off = 1; off < 64; off <<= 1) {
            unsigned t = __shfl_up(s, off);
            if (lane >= off) s += t;
        }
        if (lane == 63) wsum[w] = s;
        __syncthreads();
        if (tid < 16) {
            unsigned t = wsum[tid];
            #pragma unroll
            for (int off = 1; off < 16; off <<= 1) {
                unsigned u = __shfl_up(t, off);
                if (tid >= off) t += u;
            }
            wsum[tid] = t;
        }
        __syncthreads();
        unsigned woff = (w == 0) ? 0u : wsum[w - 1];
        unsigned excl = carry + woff + (s - t3);
        if (i < n)     cur[i]     = excl;
        if (i + 1 < n) cur[i + 1] = excl + t0;
        if (i + 2 < n) cur[i + 2] = excl + t1;
        if (i + 3 < n) cur[i + 3] = excl + t2;
        unsigned tot = wsum[15];
        __syncthreads();
        carry += tot;
    }
}

__global__ void scatter_k(const int* __restrict__ ei, const float* __restrict__ ea,
                          unsigned* __restrict__ cur, uint4* __restrict__ rec, int E) {
    int e = blockIdx.x * 256 + threadIdx.x;
    if (e >= E) return;
    int d = ei[E + e];
    unsigned pos = atomicAdd(&cur[d], 1u);
    uint4 r;
    r.x = (unsigned)ei[e];
    r.y = __builtin_bit_cast(unsigned, ea[(size_t)e * 3 + 0]);
    r.z = __builtin_bit_cast(unsigned, ea[(size_t)e * 3 + 1]);
    r.w = __builtin_bit_cast(unsigned, ea[(size_t)e * 3 + 2]);
    rec[pos] = r;
}

// ---------------- S1 = x@W1[:128], T = x@W1[128:256], B from LDS ----------------
__global__ __launch_bounds__(256, 2)
void s1t_gemm(const float* __restrict__ x, const unsigned short* __restrict__ W1f,
              unsigned short* __restrict__ S1b, unsigned short* __restrict__ Tb, int N)
{
    __shared__ alignas(16) unsigned short sW[32768];
    const int tid  = threadIdx.x;
    for (int i = tid; i < 4096; i += 256)
        ((uint4*)sW)[i] = ((const uint4*)W1f)[i];
    __syncthreads();

    const int lane = tid & 63;
    const int wid  = tid >> 6;
    const int n0   = (blockIdx.x * 4 + wid) * 16;
    if (n0 >= N) return;
    const int arow = lane & 15;
    const int g4   = lane >> 4;

    int nr = n0 + arow; if (nr >= N) nr = N - 1;
    const float* px = x + (size_t)nr * 128 + g4 * 8;

    short8 af[4];
    #pragma unroll
    for (int ks = 0; ks < 4; ++ks) {
        float4 v0 = *(const float4*)(px + ks * 32);
        float4 v1 = *(const float4*)(px + ks * 32 + 4);
        float v[8] = { v0.x, v0.y, v0.z, v0.w, v1.x, v1.y, v1.z, v1.w };
        #pragma unroll
        for (int j = 0; j < 8; ++j) af[ks][j] = (short)f2bf(v[j]);
    }

    f32x4 s1[8], tt[8];
    #pragma unroll
    for (int i = 0; i < 8; ++i) { s1[i] = (f32x4)0.f; tt[i] = (f32x4)0.f; }
    #pragma unroll
    for (int ks = 0; ks < 4; ++ks) {
        #pragma unroll
        for (int nt = 0; nt < 8; ++nt) {
            short8 b1 = *(const short8*)(sW + (size_t)((ks * 8 + nt) * 64 + lane) * 8);
            short8 b2 = *(const short8*)(sW + (size_t)(((ks + 4) * 8 + nt) * 64 + lane) * 8);
            s1[nt] = __builtin_amdgcn_mfma_f32_16x16x32_bf16(af[ks], b1, s1[nt], 0, 0, 0);
            tt[nt] = __builtin_amdgcn_mfma_f32_16x16x32_bf16(af[ks], b2, tt[nt], 0, 0, 0);
        }
    }
    #pragma unroll
    for (int nt = 0; nt < 8; ++nt) {
        int col = nt * 16 + arow;
        #pragma unroll
        for (int r = 0; r < 4; ++r) {
            int node = n0 + g4 * 4 + r;
            if (node < N) {
                S1b[(size_t)node * 128 + col] = f2bf(s1[nt][r]);
                Tb [(size_t)node * 128 + col] = f2bf(tt[nt][r]);
            }
        }
    }
}

// ---------------- CSR edge kernel: rec depth-4, S1 depth-2 pipeline, zero atomics ----------------
__global__ __launch_bounds__(256, 8)
void csr_edge_k(const unsigned short* __restrict__ S1b, const unsigned short* __restrict__ Tb,
                const uint4* __restrict__ rec,
                const unsigned* __restrict__ cnt, const unsigned* __restrict__ cur,
                const float* __restrict__ W1tail, const float* __restrict__ bm1,
                float* __restrict__ HS, int N)
{
    const int lane = threadIdx.x & 63;
    const int wid  = threadIdx.x >> 6;
    const int gw   = blockIdx.x * 4 + wid;
    const int stride = gridDim.x * 4;
    const int c2 = lane * 2;

    const float w00 = W1tail[c2],       w01 = W1tail[c2 + 1];
    const float w10 = W1tail[128 + c2], w11 = W1tail[128 + c2 + 1];
    const float w20 = W1tail[256 + c2], w21 = W1tail[256 + c2 + 1];
    const float b0  = bm1[c2],          b1v = bm1[c2 + 1];

    for (int d = gw; d < N; d += stride) {
        int e1 = (int)cur[d];
        int c  = (int)cnt[d];
        int e0 = e1 - c;
        unsigned tv = *(const unsigned*)(Tb + (size_t)d * 128 + c2);
        float t0 = bf2f((unsigned short)(tv & 0xffff)) + b0;
        float t1 = bf2f((unsigned short)(tv >> 16))    + b1v;
        float a0 = 0.f, a1 = 0.f;
        if (c > 0) {
            uint4 r0 = rec[e0];
            uint4 r1 = (e0 + 1 < e1) ? rec[e0 + 1] : r0;
            uint4 r2 = (e0 + 2 < e1) ? rec[e0 + 2] : r0;
            uint4 r3 = (e0 + 3 < e1) ? rec[e0 + 3] : r0;
            unsigned s0 = *(const unsigned*)(S1b + (size_t)r0.x * 128 + c2);
            unsigned s1 = (e0 + 1 < e1)
                ? *(const unsigned*)(S1b + (size_t)r1.x * 128 + c2) : 0u;
            for (int e = e0; e < e1; ++e) {
                float x0 = __builtin_bit_cast(float, r0.y);
                float x1 = __builtin_bit_cast(float, r0.z);
                float x2 = __builtin_bit_cast(float, r0.w);
                float h0 = bf2f((unsigned short)(s0 & 0xffff)) + t0;
                float h1 = bf2f((unsigned short)(s0 >> 16))    + t1;
                h0 = fmaf(x0, w00, h0); h0 = fmaf(x1, w10, h0); h0 = fmaf(x2, w20, h0);
                h1 = fmaf(x0, w01, h1); h1 = fmaf(x1, w11, h1); h1 = fmaf(x2, w21, h1);
                a0 += fmaxf(h0, 0.f);
                a1 += fmaxf(h1, 0.f);
                // shift pipeline: rec depth-4, S1 depth-2
                r0 = r1; r1 = r2; r2 = r3;
                if (e + 4 < e1) r3 = rec[e + 4];
                s0 = s1;
                if (e + 2 < e1) s1 = *(const unsigned*)(S1b + (size_t)r1.x * 128 + c2);
            }
        }
        float2 o; o.x = a0; o.y = a1;
        *(float2*)(HS + (size_t)d * 128 + c2) = o;
    }
}

// tier-B fallback: per-edge atomics from raw inputs (HS pre-zeroed)
__global__ __launch_bounds__(256, 8)
void atomic_edge_k(const unsigned short* __restrict__ S1b, const unsigned short* __restrict__ Tb,
                   const int* __restrict__ ei, const float* __restrict__ ea,
                   const float* __restrict__ W1tail, const float* __restrict__ bm1,
                   float* __restrict__ HS, int E)
{
    const int lane = threadIdx.x & 63;
    const int wid  = threadIdx.x >> 6;
    const int gw   = blockIdx.x * 4 + wid;
    const int stride = gridDim.x * 4;
    const int c2 = lane * 2;

    const float w00 = W1tail[c2],       w01 = W1tail[c2 + 1];
    const float w10 = W1tail[128 + c2], w11 = W1tail[128 + c2 + 1];
    const float w20 = W1tail[256 + c2], w21 = W1tail[256 + c2 + 1];
    const float b0  = bm1[c2],          b1v = bm1[c2 + 1];

    for (int e = gw; e < E; e += stride) {
        int s = ei[e], d = ei[E + e];
        float x0 = ea[(size_t)e * 3 + 0];
        float x1 = ea[(size_t)e * 3 + 1];
        float x2 = ea[(size_t)e * 3 + 2];
        unsigned tv = *(const unsigned*)(Tb + (size_t)d * 128 + c2);
        unsigned sv = *(const unsigned*)(S1b + (size_t)s * 128 + c2);
        float h0 = bf2f((unsigned short)(sv & 0xffff)) + bf2f((unsigned short)(tv & 0xffff)) + b0;
        float h1 = bf2f((unsigned short)(sv >> 16))    + bf2f((unsigned short)(tv >> 16))    + b1v;
        h0 = fmaf(x0, w00, h0); h0 = fmaf(x1, w10, h0); h0 = fmaf(x2, w20, h0);
        h1 = fmaf(x0, w01, h1); h1 = fmaf(x1, w11, h1); h1 = fmaf(x2, w21, h1);
        unsafeAtomicAdd(HS + (size_t)d * 128 + c2,     fmaxf(h0, 0.f));
        unsafeAtomicAdd(HS + (size_t)d * 128 + c2 + 1, fmaxf(h1, 0.f));
    }
}

// ---------------- Node kernel: ping-pong weight staging, 2-pass MFMA ----------------
__global__ __launch_bounds__(256, 2)
void node_mfma(const float* __restrict__ x,
               const float* __restrict__ HS,
               const unsigned* __restrict__ cnt,
               const float* __restrict__ bcg, const float* __restrict__ bcu,
               const unsigned short* __restrict__ WgH,
               const unsigned short* __restrict__ Wu1H,
               const unsigned short* __restrict__ Wu2H,
               const float* __restrict__ bg, const float* __restrict__ bu1,
               const float* __restrict__ bu2,
               const float* __restrict__ gamma, const float* __restrict__ beta,
               float* __restrict__ out, int N)
{
    // [0,16K) buf0, [16K,32K) buf1 (weight ping-pong), [32K,64K) Hs (4 waves x 8 KB)
    __shared__ alignas(16) char smem[65536];

    const int tid  = threadIdx.x;
    const int lane = tid & 63;
    const int wid  = tid >> 6;
    const int n0   = (blockIdx.x * 4 + wid) * 16;
    // NO early return: block barriers are cooperative.

    const int arow = lane & 15;
    const int g4   = lane >> 4;

    int nr = n0 + arow; if (nr >= N) nr = N - 1;
    if (nr < 0) nr = 0;
    const float* px = x  + (size_t)nr * 128 + g4 * 8;
    const float* pa = HS + (size_t)nr * 128 + g4 * 8;

    short8 ah[8], al[8];
    #pragma unroll
    for (int ks = 0; ks < 8; ++ks) {
        const float* p = (ks < 4) ? (px + ks * 32) : (pa + (ks - 4) * 32);
        float4 v0 = *(const float4*)p;
        float4 v1 = *(const float4*)(p + 4);
        float v[8] = { v0.x, v0.y, v0.z, v0.w, v1.x, v1.y, v1.z, v1.w };
        #pragma unroll
        for (int j = 0; j < 8; ++j) {
            unsigned short h = f2bf(v[j]);
            ah[ks][j] = (short)h;
            al[ks][j] = (short)f2bf(v[j] - bf2f(h));
        }
    }

    float degf[4];
    #pragma unroll
    for (int r = 0; r < 4; ++r) {
        int node = n0 + g4 * 4 + r;
        degf[r] = (node >= 0 && node < N) ? (float)cnt[node] : 0.f;
    }

    uint4* buf0 = (uint4*)smem;
    uint4* buf1 = (uint4*)(smem + 16384);

    // prologue: stage ks=0 into buf0 (gate 8K @ [0,8K), u1 8K @ [8K,16K))
    {
        int idx = tid, idx2 = tid + 256;
        buf0[idx]        = ((const uint4*)WgH )[idx];
        buf0[idx2]       = ((const uint4*)WgH )[idx2];
        buf0[512 + idx]  = ((const uint4*)Wu1H)[idx];
        buf0[512 + idx2] = ((const uint4*)Wu1H)[idx2];
    }
    __syncthreads();

    // ---- gate + u1 GEMMs (K=256, 2-pass), ping-pong staging ----
    f32x4 ga[8], ua[8];
    #pragma unroll
    for (int i = 0; i < 8; ++i) { ga[i] = (f32x4)0.f; ua[i] = (f32x4)0.f; }

    for (int ks = 0; ks < 8; ++ks) {
        const unsigned short* sB = (const unsigned short*)((ks & 1) ? buf1 : buf0);
        uint4 tg0, tg1, tu0, tu1;
        if (ks < 7) {
            int idx = tid, idx2 = tid + 256;
            tg0 = ((const uint4*)WgH )[(ks + 1) * 512 + idx];
            tg1 = ((const uint4*)WgH )[(ks + 1) * 512 + idx2];
            tu0 = ((const uint4*)Wu1H)[(ks + 1) * 512 + idx];
            tu1 = ((const uint4*)Wu1H)[(ks + 1) * 512 + idx2];
        }
        #pragma unroll
        for (int nt = 0; nt < 8; ++nt) {
            size_t o = (size_t)(nt * 64 + lane) * 8;
            short8 bh = *(const short8*)(sB + o);
            short8 uh = *(const short8*)(sB + 4096 + o);
            ga[nt] = __builtin_amdgcn_mfma_f32_16x16x32_bf16(ah[ks], bh, ga[nt], 0, 0, 0);
            ga[nt] = __builtin_amdgcn_mfma_f32_16x16x32_bf16(al[ks], bh, ga[nt], 0, 0, 0);
            ua[nt] = __builtin_amdgcn_mfma_f32_16x16x32_bf16(ah[ks], uh, ua[nt], 0, 0, 0);
            ua[nt] = __builtin_amdgcn_mfma_f32_16x16x32_bf16(al[ks], uh, ua[nt], 0, 0, 0);
        }
        if (ks < 7) {
            uint4* nb = (ks & 1) ? buf0 : buf1;
            int idx = tid, idx2 = tid + 256;
            nb[idx]        = tg0;
            nb[idx2]       = tg1;
            nb[512 + idx]  = tu0;
            nb[512 + idx2] = tu1;
        }
        __syncthreads();
    }

    // + deg * composed-bias terms
    #pragma unroll
    for (int nt = 0; nt < 8; ++nt) {
        int col = nt * 16 + arow;
        float bgc = bcg[col], buc = bcu[col];
        #pragma unroll
        for (int r = 0; r < 4; ++r) {
            ga[nt][r] = fmaf(degf[r], bgc, ga[nt][r]);
            ua[nt][r] = fmaf(degf[r], buc, ua[nt][r]);
        }
    }

    // relu + bias, hi/lo pack into wave-private Hs at [32K,64K)
    char* Hw = smem + 32768 + wid * 8192;
    #pragma unroll
    for (int nt = 0; nt < 8; ++nt) {
        int col = nt * 16 + arow;
        float b1 = bu1[col];
        #pragma unroll
        for (int r = 0; r < 4; ++r) {
            int row = g4 * 4 + r;
            float u = fmaxf(ua[nt][r] + b1, 0.f);
            unsigned short h = f2bf(u);
            unsigned short l = f2bf(u - bf2f(h));
            unsigned int pk = (unsigned int)h | ((unsigned int)l << 16);
            *(unsigned int*)(Hw + row * 512 + ((col * 4) ^ ((row & 15) << 4))) = pk;
        }
    }

    // gate sigmoid
    #pragma unroll
    for (int nt = 0; nt < 8; ++nt) {
        int col = nt * 16 + arow;
        float b = bg[col];
        #pragma unroll
        for (int r = 0; r < 4; ++r)
            ga[nt][r] = 1.f / (1.f + expf(-(ga[nt][r] + b)));
    }

    // stage u2 ks=0 into buf0 (needs barrier: buf1 was read in ks=7 phase by all)
    {
        int idx = tid, idx2 = tid + 256;
        buf0[idx]  = ((const uint4*)Wu2H)[idx];
        buf0[idx2] = ((const uint4*)Wu2H)[idx2];
    }
    __syncthreads();

    // ---- u2 GEMM (K=128, 2-pass), ping-pong 8KB chunks ----
    f32x4 u2[8];
    #pragma unroll
    for (int i = 0; i < 8; ++i) u2[i] = (f32x4)0.f;
    for (int ks = 0; ks < 4; ++ks) {
        const unsigned short* sB = (const unsigned short*)((ks & 1) ? buf1 : buf0);
        uint4 t0v, t1v;
        if (ks < 3) {
            int idx = tid, idx2 = tid + 256;
            t0v = ((const uint4*)Wu2H)[(ks + 1) * 512 + idx];
            t1v = ((const uint4*)Wu2H)[(ks + 1) * 512 + idx2];
        }
        int b0 = ks * 128 + g4 * 32;
        unsigned int q0[4], q1[4];
        *(uint4*)q0 = *(const uint4*)(Hw + arow * 512 + ( b0       ^ (arow << 4)));
        *(uint4*)q1 = *(const uint4*)(Hw + arow * 512 + ((b0 + 16) ^ (arow << 4)));
        short8 a2h, a2l;
        #pragma unroll
        for (int j = 0; j < 4; ++j) {
            a2h[j]     = (short)(q0[j] & 0xffff);
            a2l[j]     = (short)(q0[j] >> 16);
            a2h[4 + j] = (short)(q1[j] & 0xffff);
            a2l[4 + j] = (short)(q1[j] >> 16);
        }
        #pragma unroll
        for (int nt = 0; nt < 8; ++nt) {
            size_t o = (size_t)(nt * 64 + lane) * 8;
            short8 bh = *(const short8*)(sB + o);
            u2[nt] = __builtin_amdgcn_mfma_f32_16x16x32_bf16(a2h, bh, u2[nt], 0, 0, 0);
            u2[nt] = __builtin_amdgcn_mfma_f32_16x16x32_bf16(a2l, bh, u2[nt], 0, 0, 0);
        }
        if (ks < 3) {
            uint4* nb = (ks & 1) ? buf0 : buf1;
            int idx = tid, idx2 = tid + 256;
            nb[idx]  = t0v;
            nb[idx2] = t1v;
        }
        __syncthreads();
    }

    // ---- epilogue: gating + LayerNorm + store ----
    float s[4]  = {0.f, 0.f, 0.f, 0.f};
    float ss[4] = {0.f, 0.f, 0.f, 0.f};
    #pragma unroll
    for (int nt = 0; nt < 8; ++nt) {
        int col = nt * 16 + arow;
        float b2 = bu2[col];
        #pragma unroll
        for (int r = 0; r < 4; ++r) {
            int node = n0 + g4 * 4 + r;
            int nc = (node >= 0 && node < N) ? node : 0;
            float xv = x[(size_t)nc * 128 + col];
            float g  = ga[nt][r];
            float o  = g * (u2[nt][r] + b2) + (1.f - g) * xv;
            u2[nt][r] = o;
            s[r]  += o;
            ss[r] += o * o;
        }
    }
    #pragma unroll
    for (int off = 8; off >= 1; off >>= 1) {
        #pragma unroll
        for (int r = 0; r < 4; ++r) {
            s[r]  += __shfl_xor(s[r],  off);
            ss[r] += __shfl_xor(ss[r], off);
        }
    }
    float mu[4], rstd[4];
    #pragma unroll
    for (int r = 0; r < 4; ++r) {
        mu[r] = s[r] * (1.f / 128.f);
        float var = ss[r] * (1.f / 128.f) - mu[r] * mu[r];
        rstd[r] = rsqrtf(var + 1e-5f);
    }
    #pragma unroll
    for (int nt = 0; nt < 8; ++nt) {
        int col = nt * 16 + arow;
        float gm = gamma[col], bt = beta[col];
        #pragma unroll
        for (int r = 0; r < 4; ++r) {
            int node = n0 + g4 * 4 + r;
            if (node >= 0 && node < N)
                out[(size_t)node * 128 + col] = (u2[nt][r] - mu[r]) * rstd[r] * gm + bt;
        }
    }
}

extern "C" void kernel_launch(void* const* d_in, const int* in_sizes, int n_in,
                              void* d_out, int out_size, void* d_ws, size_t ws_size,
                              hipStream_t stream)
{
    const float* x    = (const float*)d_in[0];
    const int*   ei   = (const int*)  d_in[1];
    const float* ea   = (const float*)d_in[2];
    const float* Wm1  = (const float*)d_in[3];
    const float* bm1  = (const float*)d_in[4];
    const float* Wm2  = (const float*)d_in[5];
    const float* bm2  = (const float*)d_in[6];
    const float* Wg   = (const float*)d_in[7];
    const float* bg   = (const float*)d_in[8];
    const float* Wu1  = (const float*)d_in[9];
    const float* bu1  = (const float*)d_in[10];
    const float* Wu2  = (const float*)d_in[11];
    const float* bu2  = (const float*)d_in[12];
    const float* gmma = (const float*)d_in[13];
    const float* beta = (const float*)d_in[14];
    float* out = (float*)d_out;

    const int N = in_sizes[0] / HID;
    const int E = in_sizes[1] / 2;

    // workspace carve-up
    unsigned short* S1b  = (unsigned short*)d_ws;            // N*128 bf16
    unsigned short* Tb   = S1b + (size_t)N * HID;            // N*128 bf16
    float*          HS   = (float*)(Tb + (size_t)N * HID);   // N*128 f32
    unsigned short* W1f  = (unsigned short*)(HS + (size_t)N * HID); // 32768
    unsigned short* WgH  = W1f + 32768;
    unsigned short* Wu1H = WgH + 32768;
    unsigned short* Wu2H = Wu1H + 32768;
    float*          bcg  = (float*)(Wu2H + 16384);           // 128
    float*          bcu  = bcg + 128;                        // 128
    unsigned*       cnt  = (unsigned*)(bcu + 128);           // N
    unsigned*       cur  = cnt + N;                          // N
    uint4*          rec  = (uint4*)(cur + N);
    rec = (uint4*)(((size_t)rec + 15) & ~(size_t)15);
    size_t need_sort = (size_t)((char*)(rec + E) - (char*)d_ws);
    const bool tierA = (ws_size >= need_sort);

    // fused weights prep + cnt zero
    int zblocks = ((N + 3) / 4 + 255) / 256;
    prep_all<<<dim3(280 + zblocks), dim3(256), 0, stream>>>(
        Wm1, Wg, Wu1, Wm2, bm2, Wu2, W1f, WgH, bcg, Wu1H, bcu, Wu2H, cnt, N);

    // dense per-node S1/T
    s1t_gemm<<<dim3((N + 63) / 64), dim3(256), 0, stream>>>(x, W1f, S1b, Tb, N);

    // degree histogram
    hist_k<<<dim3((E + 255) / 256), dim3(256), 0, stream>>>(ei, cnt, E);

    if (tierA) {
        scan_k<<<dim3(1), dim3(1024), 0, stream>>>(cnt, cur, N);
        scatter_k<<<dim3((E + 255) / 256), dim3(256), 0, stream>>>(ei, ea, cur, rec, E);
        csr_edge_k<<<dim3(2048), dim3(256), 0, stream>>>(
            S1b, Tb, rec, cnt, cur, Wm1 + 256 * HID, bm1, HS, N);
    } else {
        hipMemsetAsync(HS, 0, (size_t)N * HID * sizeof(float), stream);
        atomic_edge_k<<<dim3(2048), dim3(256), 0, stream>>>(
            S1b, Tb, ei, ea, Wm1 + 256 * HID, bm1, HS, E);
    }

    node_mfma<<<dim3((N + 63) / 64), dim3(256), 0, stream>>>(
        x, HS, cnt, bcg, bcu,
        WgH, Wu1H, Wu2H,
        bg, bu1, bu2, gmma, beta, out, N);
}

// Round 19
// 199.586 us; speedup vs baseline: 1.5001x; 1.1453x over previous
//
#include <hip/hip_runtime.h>
#include <hip/hip_bf16.h>

#define HID 128

typedef __attribute__((ext_vector_type(8))) short short8;
typedef __attribute__((ext_vector_type(4))) float f32x4;

__device__ __forceinline__ unsigned short f2bf(float f) {
    unsigned int u = __builtin_bit_cast(unsigned int, f);
    u += 0x7FFFu + ((u >> 16) & 1u);
    return (unsigned short)(u >> 16);
}
__device__ __forceinline__ float bf2f(unsigned short h) {
    unsigned int u = ((unsigned int)h) << 16;
    return __builtin_bit_cast(float, u);
}

// ---------------- fused prep: W1f | comp(Wg) | comp(Wu1) | Wu2 frags | zero cnt ----------------
__global__ void prep_all(const float* __restrict__ Wm1,
                         const float* __restrict__ Wg,  const float* __restrict__ Wu1,
                         const float* __restrict__ Wm2, const float* __restrict__ bm2,
                         const float* __restrict__ Wu2,
                         unsigned short* __restrict__ W1f,
                         unsigned short* __restrict__ WgH,  float* __restrict__ bcg,
                         unsigned short* __restrict__ Wu1H, float* __restrict__ bcu,
                         unsigned short* __restrict__ Wu2H,
                         unsigned* __restrict__ cnt, int N)
{
    int b = blockIdx.x;
    if (b < 16) {
        int t = b * 256 + threadIdx.x;
        if (t < 4096) {
            int lane = t & 63, nt = (t >> 6) & 7, ks = t >> 9;
            int kb  = ks * 32 + ((lane >> 4) << 3);
            int col = (nt << 4) + (lane & 15);
            union { unsigned short u[8]; uint4 q; } p;
            #pragma unroll
            for (int j = 0; j < 8; ++j) p.u[j] = f2bf(Wm1[(size_t)(kb + j) * 128 + col]);
            *(uint4*)(W1f + (size_t)t * 8) = p.q;
        }
    } else if (b < 272) {
        const bool isG = (b < 144);
        const float* Wtop = isG ? Wg : Wu1;
        unsigned short* Wh = isG ? WgH : Wu1H;
        float* bc = isG ? bcg : bcu;
        int lb = b - (isG ? 16 : 144);
        int t = lb * 256 + threadIdx.x;
        if (t < 32768) {
            int j = t & 7, lane = (t >> 3) & 63, nt = (t >> 9) & 7, ks = t >> 12;
            int r   = ks * 32 + ((lane >> 4) << 3) + j;
            int col = (nt << 4) + (lane & 15);
            float w;
            if (r < 128) {
                w = Wtop[(size_t)r * 128 + col];
            } else {
                const float* a = Wm2 + (size_t)(r - 128) * 128;
                float s = 0.f;
                for (int k = 0; k < 128; ++k)
                    s = fmaf(a[k], Wtop[(size_t)(128 + k) * 128 + col], s);
                w = s;
            }
            Wh[t] = f2bf(w);
        }
        if (lb == 0 && threadIdx.x < 128) {
            int jj = threadIdx.x;
            float s = 0.f;
            for (int k = 0; k < 128; ++k)
                s = fmaf(bm2[k], Wtop[(size_t)(128 + k) * 128 + jj], s);
            bc[jj] = s;
        }
    } else if (b < 280) {
        int t = (b - 272) * 256 + threadIdx.x;
        if (t < 2048) {
            int lane = t & 63, nt = (t >> 6) & 7, ks = t >> 9;
            int kb  = ks * 32 + ((lane >> 4) << 3);
            int col = (nt << 4) + (lane & 15);
            union { unsigned short u[8]; uint4 q; } p;
            #pragma unroll
            for (int j = 0; j < 8; ++j) p.u[j] = f2bf(Wu2[(size_t)(kb + j) * 128 + col]);
            *(uint4*)(Wu2H + (size_t)t * 8) = p.q;
        }
    } else {
        int t = (b - 280) * 256 + threadIdx.x;
        int i = t * 4;
        if (i + 3 < N) {
            *(uint4*)(cnt + i) = make_uint4(0u, 0u, 0u, 0u);
        } else {
            for (int k = 0; k < 4 && i + k < N; ++k) cnt[i + k] = 0u;
        }
    }
}

// ---------------- scan / scatter ----------------
__global__ void scan_k(const unsigned* __restrict__ cnt, unsigned* __restrict__ cur, int n) {
    __shared__ unsigned wsum[16];
    int tid = threadIdx.x, lane = tid & 63, w = tid >> 6;
    unsigned carry = 0;
    for (int base = 0; base < n; base += 4096) {
        int i = base + tid * 4;
        unsigned v0 = 0, v1 = 0, v2 = 0, v3 = 0;
        if (i + 3 < n) {
            uint4 q = *(const uint4*)(cnt + i);
            v0 = q.x; v1 = q.y; v2 = q.z; v3 = q.w;
        } else {
            if (i < n)     v0 = cnt[i];
            if (i + 1 < n) v1 = cnt[i + 1];
            if (i + 2 < n) v2 = cnt[i + 2];
            if (i + 3 < n) v3 = cnt[i + 3];
        }
        unsigned t0 = v0, t1 = t0 + v1, t2 = t1 + v2, t3 = t2 + v3;
        unsigned s = t3;
        #pragma unroll
        for (int off = 1; off < 64; off <<= 1) {
            unsigned t = __shfl_up(s, off);
            if (lane >= off) s += t;
        }
        if (lane == 63) wsum[w] = s;
        __syncthreads();
        if (tid < 16) {
            unsigned t = wsum[tid];
            #pragma unroll
            for (int off = 1; off < 16; off <<= 1) {
                unsigned u = __shfl_up(t, off);
                if (tid >= off) t += u;
            }
            wsum[tid] = t;
        }
        __syncthreads();
        unsigned woff = (w == 0) ? 0u : wsum[w - 1];
        unsigned excl = carry + woff + (s - t3);
        if (i < n)     cur[i]     = excl;
        if (i + 1 < n) cur[i + 1] = excl + t0;
        if (i + 2 < n) cur[i + 2] = excl + t1;
        if (i + 3 < n) cur[i + 3] = excl + t2;
        unsigned tot = wsum[15];
        __syncthreads();
        carry += tot;
    }
}

__global__ void scatter_k(const int* __restrict__ ei, const float* __restrict__ ea,
                          unsigned* __restrict__ cur, uint4* __restrict__ rec, int E) {
    int e = blockIdx.x * 256 + threadIdx.x;
    if (e >= E) return;
    int d = ei[E + e];
    unsigned pos = atomicAdd(&cur[d], 1u);
    uint4 r;
    r.x = (unsigned)ei[e];
    r.y = __builtin_bit_cast(unsigned, ea[(size_t)e * 3 + 0]);
    r.z = __builtin_bit_cast(unsigned, ea[(size_t)e * 3 + 1]);
    r.w = __builtin_bit_cast(unsigned, ea[(size_t)e * 3 + 2]);
    rec[pos] = r;
}

// ---------------- S1/T GEMM with fused degree-histogram ----------------
__global__ __launch_bounds__(256, 2)
void s1t_hist_k(const float* __restrict__ x, const unsigned short* __restrict__ W1f,
                unsigned short* __restrict__ S1b, unsigned short* __restrict__ Tb, int N,
                const int* __restrict__ ei, unsigned* __restrict__ cnt, int E)
{
    __shared__ alignas(16) unsigned short sW[32768];
    const int tid  = threadIdx.x;

    // fused histogram: issue early, completes under the GEMM
    for (int e = blockIdx.x * 256 + tid; e < E; e += gridDim.x * 256)
        atomicAdd(&cnt[ei[E + e]], 1u);

    for (int i = tid; i < 4096; i += 256)
        ((uint4*)sW)[i] = ((const uint4*)W1f)[i];
    __syncthreads();

    const int lane = tid & 63;
    const int wid  = tid >> 6;
    const int n0   = (blockIdx.x * 4 + wid) * 16;
    if (n0 >= N) return;
    const int arow = lane & 15;
    const int g4   = lane >> 4;

    int nr = n0 + arow; if (nr >= N) nr = N - 1;
    const float* px = x + (size_t)nr * 128 + g4 * 8;

    short8 af[4];
    #pragma unroll
    for (int ks = 0; ks < 4; ++ks) {
        float4 v0 = *(const float4*)(px + ks * 32);
        float4 v1 = *(const float4*)(px + ks * 32 + 4);
        float v[8] = { v0.x, v0.y, v0.z, v0.w, v1.x, v1.y, v1.z, v1.w };
        #pragma unroll
        for (int j = 0; j < 8; ++j) af[ks][j] = (short)f2bf(v[j]);
    }

    f32x4 s1[8], tt[8];
    #pragma unroll
    for (int i = 0; i < 8; ++i) { s1[i] = (f32x4)0.f; tt[i] = (f32x4)0.f; }
    #pragma unroll
    for (int ks = 0; ks < 4; ++ks) {
        #pragma unroll
        for (int nt = 0; nt < 8; ++nt) {
            short8 b1 = *(const short8*)(sW + (size_t)((ks * 8 + nt) * 64 + lane) * 8);
            short8 b2 = *(const short8*)(sW + (size_t)(((ks + 4) * 8 + nt) * 64 + lane) * 8);
            s1[nt] = __builtin_amdgcn_mfma_f32_16x16x32_bf16(af[ks], b1, s1[nt], 0, 0, 0);
            tt[nt] = __builtin_amdgcn_mfma_f32_16x16x32_bf16(af[ks], b2, tt[nt], 0, 0, 0);
        }
    }
    #pragma unroll
    for (int nt = 0; nt < 8; ++nt) {
        int col = nt * 16 + arow;
        #pragma unroll
        for (int r = 0; r < 4; ++r) {
            int node = n0 + g4 * 4 + r;
            if (node < N) {
                S1b[(size_t)node * 128 + col] = f2bf(s1[nt][r]);
                Tb [(size_t)node * 128 + col] = f2bf(tt[nt][r]);
            }
        }
    }
}

// ---------------- CSR edge kernel: chunk-of-4 unroll (no register queue) ----------------
__global__ __launch_bounds__(256, 8)
void csr_edge_k(const unsigned short* __restrict__ S1b, const unsigned short* __restrict__ Tb,
                const uint4* __restrict__ rec,
                const unsigned* __restrict__ cnt, const unsigned* __restrict__ cur,
                const float* __restrict__ W1tail, const float* __restrict__ bm1,
                float* __restrict__ HS, int N)
{
    const int lane = threadIdx.x & 63;
    const int wid  = threadIdx.x >> 6;
    const int gw   = blockIdx.x * 4 + wid;
    const int stride = gridDim.x * 4;
    const int c2 = lane * 2;

    const float w00 = W1tail[c2],       w01 = W1tail[c2 + 1];
    const float w10 = W1tail[128 + c2], w11 = W1tail[128 + c2 + 1];
    const float w20 = W1tail[256 + c2], w21 = W1tail[256 + c2 + 1];
    const float b0  = bm1[c2],          b1v = bm1[c2 + 1];

    for (int d = gw; d < N; d += stride) {
        int e1 = (int)cur[d];
        int c  = (int)cnt[d];
        int e0 = e1 - c;
        unsigned tv = *(const unsigned*)(Tb + (size_t)d * 128 + c2);
        float t0 = bf2f((unsigned short)(tv & 0xffff)) + b0;
        float t1 = bf2f((unsigned short)(tv >> 16))    + b1v;
        float a0 = 0.f, a1 = 0.f;

        int e = e0;
        for (; e + 4 <= e1; e += 4) {
            uint4 ra = rec[e];
            uint4 rb = rec[e + 1];
            uint4 rc = rec[e + 2];
            uint4 rd = rec[e + 3];
            unsigned sa = *(const unsigned*)(S1b + (size_t)ra.x * 128 + c2);
            unsigned sb = *(const unsigned*)(S1b + (size_t)rb.x * 128 + c2);
            unsigned sc = *(const unsigned*)(S1b + (size_t)rc.x * 128 + c2);
            unsigned sd = *(const unsigned*)(S1b + (size_t)rd.x * 128 + c2);
            {
                float h0 = bf2f((unsigned short)(sa & 0xffff)) + t0;
                float h1 = bf2f((unsigned short)(sa >> 16))    + t1;
                float x0 = __builtin_bit_cast(float, ra.y);
                float x1 = __builtin_bit_cast(float, ra.z);
                float x2 = __builtin_bit_cast(float, ra.w);
                h0 = fmaf(x0, w00, h0); h0 = fmaf(x1, w10, h0); h0 = fmaf(x2, w20, h0);
                h1 = fmaf(x0, w01, h1); h1 = fmaf(x1, w11, h1); h1 = fmaf(x2, w21, h1);
                a0 += fmaxf(h0, 0.f); a1 += fmaxf(h1, 0.f);
            }
            {
                float h0 = bf2f((unsigned short)(sb & 0xffff)) + t0;
                float h1 = bf2f((unsigned short)(sb >> 16))    + t1;
                float x0 = __builtin_bit_cast(float, rb.y);
                float x1 = __builtin_bit_cast(float, rb.z);
                float x2 = __builtin_bit_cast(float, rb.w);
                h0 = fmaf(x0, w00, h0); h0 = fmaf(x1, w10, h0); h0 = fmaf(x2, w20, h0);
                h1 = fmaf(x0, w01, h1); h1 = fmaf(x1, w11, h1); h1 = fmaf(x2, w21, h1);
                a0 += fmaxf(h0, 0.f); a1 += fmaxf(h1, 0.f);
            }
            {
                float h0 = bf2f((unsigned short)(sc & 0xffff)) + t0;
                float h1 = bf2f((unsigned short)(sc >> 16))    + t1;
                float x0 = __builtin_bit_cast(float, rc.y);
                float x1 = __builtin_bit_cast(float, rc.z);
                float x2 = __builtin_bit_cast(float, rc.w);
                h0 = fmaf(x0, w00, h0); h0 = fmaf(x1, w10, h0); h0 = fmaf(x2, w20, h0);
                h1 = fmaf(x0, w01, h1); h1 = fmaf(x1, w11, h1); h1 = fmaf(x2, w21, h1);
                a0 += fmaxf(h0, 0.f); a1 += fmaxf(h1, 0.f);
            }
            {
                float h0 = bf2f((unsigned short)(sd & 0xffff)) + t0;
                float h1 = bf2f((unsigned short)(sd >> 16))    + t1;
                float x0 = __builtin_bit_cast(float, rd.y);
                float x1 = __builtin_bit_cast(float, rd.z);
                float x2 = __builtin_bit_cast(float, rd.w);
                h0 = fmaf(x0, w00, h0); h0 = fmaf(x1, w10, h0); h0 = fmaf(x2, w20, h0);
                h1 = fmaf(x0, w01, h1); h1 = fmaf(x1, w11, h1); h1 = fmaf(x2, w21, h1);
                a0 += fmaxf(h0, 0.f); a1 += fmaxf(h1, 0.f);
            }
        }
        for (; e < e1; ++e) {
            uint4 r = rec[e];
            unsigned sv = *(const unsigned*)(S1b + (size_t)r.x * 128 + c2);
            float h0 = bf2f((unsigned short)(sv & 0xffff)) + t0;
            float h1 = bf2f((unsigned short)(sv >> 16))    + t1;
            float x0 = __builtin_bit_cast(float, r.y);
            float x1 = __builtin_bit_cast(float, r.z);
            float x2 = __builtin_bit_cast(float, r.w);
            h0 = fmaf(x0, w00, h0); h0 = fmaf(x1, w10, h0); h0 = fmaf(x2, w20, h0);
            h1 = fmaf(x0, w01, h1); h1 = fmaf(x1, w11, h1); h1 = fmaf(x2, w21, h1);
            a0 += fmaxf(h0, 0.f); a1 += fmaxf(h1, 0.f);
        }

        float2 o; o.x = a0; o.y = a1;
        *(float2*)(HS + (size_t)d * 128 + c2) = o;
    }
}

// tier-B fallback: per-edge atomics from raw inputs (HS pre-zeroed)
__global__ __launch_bounds__(256, 8)
void atomic_edge_k(const unsigned short* __restrict__ S1b, const unsigned short* __restrict__ Tb,
                   const int* __restrict__ ei, const float* __restrict__ ea,
                   const float* __restrict__ W1tail, const float* __restrict__ bm1,
                   float* __restrict__ HS, int E)
{
    const int lane = threadIdx.x & 63;
    const int wid  = threadIdx.x >> 6;
    const int gw   = blockIdx.x * 4 + wid;
    const int stride = gridDim.x * 4;
    const int c2 = lane * 2;

    const float w00 = W1tail[c2],       w01 = W1tail[c2 + 1];
    const float w10 = W1tail[128 + c2], w11 = W1tail[128 + c2 + 1];
    const float w20 = W1tail[256 + c2], w21 = W1tail[256 + c2 + 1];
    const float b0  = bm1[c2],          b1v = bm1[c2 + 1];

    for (int e = gw; e < E; e += stride) {
        int s = ei[e], d = ei[E + e];
        float x0 = ea[(size_t)e * 3 + 0];
        float x1 = ea[(size_t)e * 3 + 1];
        float x2 = ea[(size_t)e * 3 + 2];
        unsigned tv = *(const unsigned*)(Tb + (size_t)d * 128 + c2);
        unsigned sv = *(const unsigned*)(S1b + (size_t)s * 128 + c2);
        float h0 = bf2f((unsigned short)(sv & 0xffff)) + bf2f((unsigned short)(tv & 0xffff)) + b0;
        float h1 = bf2f((unsigned short)(sv >> 16))    + bf2f((unsigned short)(tv >> 16))    + b1v;
        h0 = fmaf(x0, w00, h0); h0 = fmaf(x1, w10, h0); h0 = fmaf(x2, w20, h0);
        h1 = fmaf(x0, w01, h1); h1 = fmaf(x1, w11, h1); h1 = fmaf(x2, w21, h1);
        unsafeAtomicAdd(HS + (size_t)d * 128 + c2,     fmaxf(h0, 0.f));
        unsafeAtomicAdd(HS + (size_t)d * 128 + c2 + 1, fmaxf(h1, 0.f));
    }
}

// ---------------- Node kernel: ping-pong weight staging, 2-pass MFMA ----------------
__global__ __launch_bounds__(256, 2)
void node_mfma(const float* __restrict__ x,
               const float* __restrict__ HS,
               const unsigned* __restrict__ cnt,
               const float* __restrict__ bcg, const float* __restrict__ bcu,
               const unsigned short* __restrict__ WgH,
               const unsigned short* __restrict__ Wu1H,
               const unsigned short* __restrict__ Wu2H,
               const float* __restrict__ bg, const float* __restrict__ bu1,
               const float* __restrict__ bu2,
               const float* __restrict__ gamma, const float* __restrict__ beta,
               float* __restrict__ out, int N)
{
    __shared__ alignas(16) char smem[65536];

    const int tid  = threadIdx.x;
    const int lane = tid & 63;
    const int wid  = tid >> 6;
    const int n0   = (blockIdx.x * 4 + wid) * 16;

    const int arow = lane & 15;
    const int g4   = lane >> 4;

    int nr = n0 + arow; if (nr >= N) nr = N - 1;
    if (nr < 0) nr = 0;
    const float* px = x  + (size_t)nr * 128 + g4 * 8;
    const float* pa = HS + (size_t)nr * 128 + g4 * 8;

    short8 ah[8], al[8];
    #pragma unroll
    for (int ks = 0; ks < 8; ++ks) {
        const float* p = (ks < 4) ? (px + ks * 32) : (pa + (ks - 4) * 32);
        float4 v0 = *(const float4*)p;
        float4 v1 = *(const float4*)(p + 4);
        float v[8] = { v0.x, v0.y, v0.z, v0.w, v1.x, v1.y, v1.z, v1.w };
        #pragma unroll
        for (int j = 0; j < 8; ++j) {
            unsigned short h = f2bf(v[j]);
            ah[ks][j] = (short)h;
            al[ks][j] = (short)f2bf(v[j] - bf2f(h));
        }
    }

    float degf[4];
    #pragma unroll
    for (int r = 0; r < 4; ++r) {
        int node = n0 + g4 * 4 + r;
        degf[r] = (node >= 0 && node < N) ? (float)cnt[node] : 0.f;
    }

    uint4* buf0 = (uint4*)smem;
    uint4* buf1 = (uint4*)(smem + 16384);

    {
        int idx = tid, idx2 = tid + 256;
        buf0[idx]        = ((const uint4*)WgH )[idx];
        buf0[idx2]       = ((const uint4*)WgH )[idx2];
        buf0[512 + idx]  = ((const uint4*)Wu1H)[idx];
        buf0[512 + idx2] = ((const uint4*)Wu1H)[idx2];
    }
    __syncthreads();

    f32x4 ga[8], ua[8];
    #pragma unroll
    for (int i = 0; i < 8; ++i) { ga[i] = (f32x4)0.f; ua[i] = (f32x4)0.f; }

    for (int ks = 0; ks < 8; ++ks) {
        const unsigned short* sB = (const unsigned short*)((ks & 1) ? buf1 : buf0);
        uint4 tg0, tg1, tu0, tu1;
        if (ks < 7) {
            int idx = tid, idx2 = tid + 256;
            tg0 = ((const uint4*)WgH )[(ks + 1) * 512 + idx];
            tg1 = ((const uint4*)WgH )[(ks + 1) * 512 + idx2];
            tu0 = ((const uint4*)Wu1H)[(ks + 1) * 512 + idx];
            tu1 = ((const uint4*)Wu1H)[(ks + 1) * 512 + idx2];
        }
        #pragma unroll
        for (int nt = 0; nt < 8; ++nt) {
            size_t o = (size_t)(nt * 64 + lane) * 8;
            short8 bh = *(const short8*)(sB + o);
            short8 uh = *(const short8*)(sB + 4096 + o);
            ga[nt] = __builtin_amdgcn_mfma_f32_16x16x32_bf16(ah[ks], bh, ga[nt], 0, 0, 0);
            ga[nt] = __builtin_amdgcn_mfma_f32_16x16x32_bf16(al[ks], bh, ga[nt], 0, 0, 0);
            ua[nt] = __builtin_amdgcn_mfma_f32_16x16x32_bf16(ah[ks], uh, ua[nt], 0, 0, 0);
            ua[nt] = __builtin_amdgcn_mfma_f32_16x16x32_bf16(al[ks], uh, ua[nt], 0, 0, 0);
        }
        if (ks < 7) {
            uint4* nb = (ks & 1) ? buf0 : buf1;
            int idx = tid, idx2 = tid + 256;
            nb[idx]        = tg0;
            nb[idx2]       = tg1;
            nb[512 + idx]  = tu0;
            nb[512 + idx2] = tu1;
        }
        __syncthreads();
    }

    #pragma unroll
    for (int nt = 0; nt < 8; ++nt) {
        int col = nt * 16 + arow;
        float bgc = bcg[col], buc = bcu[col];
        #pragma unroll
        for (int r = 0; r < 4; ++r) {
            ga[nt][r] = fmaf(degf[r], bgc, ga[nt][r]);
            ua[nt][r] = fmaf(degf[r], buc, ua[nt][r]);
        }
    }

    char* Hw = smem + 32768 + wid * 8192;
    #pragma unroll
    for (int nt = 0; nt < 8; ++nt) {
        int col = nt * 16 + arow;
        float b1 = bu1[col];
        #pragma unroll
        for (int r = 0; r < 4; ++r) {
            int row = g4 * 4 + r;
            float u = fmaxf(ua[nt][r] + b1, 0.f);
            unsigned short h = f2bf(u);
            unsigned short l = f2bf(u - bf2f(h));
            unsigned int pk = (unsigned int)h | ((unsigned int)l << 16);
            *(unsigned int*)(Hw + row * 512 + ((col * 4) ^ ((row & 15) << 4))) = pk;
        }
    }

    #pragma unroll
    for (int nt = 0; nt < 8; ++nt) {
        int col = nt * 16 + arow;
        float b = bg[col];
        #pragma unroll
        for (int r = 0; r < 4; ++r)
            ga[nt][r] = 1.f / (1.f + expf(-(ga[nt][r] + b)));
    }

    {
        int idx = tid, idx2 = tid + 256;
        buf0[idx]  = ((const uint4*)Wu2H)[idx];
        buf0[idx2] = ((const uint4*)Wu2H)[idx2];
    }
    __syncthreads();

    f32x4 u2[8];
    #pragma unroll
    for (int i = 0; i < 8; ++i) u2[i] = (f32x4)0.f;
    for (int ks = 0; ks < 4; ++ks) {
        const unsigned short* sB = (const unsigned short*)((ks & 1) ? buf1 : buf0);
        uint4 t0v, t1v;
        if (ks < 3) {
            int idx = tid, idx2 = tid + 256;
            t0v = ((const uint4*)Wu2H)[(ks + 1) * 512 + idx];
            t1v = ((const uint4*)Wu2H)[(ks + 1) * 512 + idx2];
        }
        int b0 = ks * 128 + g4 * 32;
        unsigned int q0[4], q1[4];
        *(uint4*)q0 = *(const uint4*)(Hw + arow * 512 + ( b0       ^ (arow << 4)));
        *(uint4*)q1 = *(const uint4*)(Hw + arow * 512 + ((b0 + 16) ^ (arow << 4)));
        short8 a2h, a2l;
        #pragma unroll
        for (int j = 0; j < 4; ++j) {
            a2h[j]     = (short)(q0[j] & 0xffff);
            a2l[j]     = (short)(q0[j] >> 16);
            a2h[4 + j] = (short)(q1[j] & 0xffff);
            a2l[4 + j] = (short)(q1[j] >> 16);
        }
        #pragma unroll
        for (int nt = 0; nt < 8; ++nt) {
            size_t o = (size_t)(nt * 64 + lane) * 8;
            short8 bh = *(const short8*)(sB + o);
            u2[nt] = __builtin_amdgcn_mfma_f32_16x16x32_bf16(a2h, bh, u2[nt], 0, 0, 0);
            u2[nt] = __builtin_amdgcn_mfma_f32_16x16x32_bf16(a2l, bh, u2[nt], 0, 0, 0);
        }
        if (ks < 3) {
            uint4* nb = (ks & 1) ? buf0 : buf1;
            int idx = tid, idx2 = tid + 256;
            nb[idx]  = t0v;
            nb[idx2] = t1v;
        }
        __syncthreads();
    }

    float s[4]  = {0.f, 0.f, 0.f, 0.f};
    float ss[4] = {0.f, 0.f, 0.f, 0.f};
    #pragma unroll
    for (int nt = 0; nt < 8; ++nt) {
        int col = nt * 16 + arow;
        float b2 = bu2[col];
        #pragma unroll
        for (int r = 0; r < 4; ++r) {
            int node = n0 + g4 * 4 + r;
            int nc = (node >= 0 && node < N) ? node : 0;
            float xv = x[(size_t)nc * 128 + col];
            float g  = ga[nt][r];
            float o  = g * (u2[nt][r] + b2) + (1.f - g) * xv;
            u2[nt][r] = o;
            s[r]  += o;
            ss[r] += o * o;
        }
    }
    #pragma unroll
    for (int off = 8; off >= 1; off >>= 1) {
        #pragma unroll
        for (int r = 0; r < 4; ++r) {
            s[r]  += __shfl_xor(s[r],  off);
            ss[r] += __shfl_xor(ss[r], off);
        }
    }
    float mu[4], rstd[4];
    #pragma unroll
    for (int r = 0; r < 4; ++r) {
        mu[r] = s[r] * (1.f / 128.f);
        float var = ss[r] * (1.f / 128.f) - mu[r] * mu[r];
        rstd[r] = rsqrtf(var + 1e-5f);
    }
    #pragma unroll
    for (int nt = 0; nt < 8; ++nt) {
        int col = nt * 16 + arow;
        float gm = gamma[col], bt = beta[col];
        #pragma unroll
        for (int r = 0; r < 4; ++r) {
            int node = n0 + g4 * 4 + r;
            if (node >= 0 && node < N)
                out[(size_t)node * 128 + col] = (u2[nt][r] - mu[r]) * rstd[r] * gm + bt;
        }
    }
}

extern "C" void kernel_launch(void* const* d_in, const int* in_sizes, int n_in,
                              void* d_out, int out_size, void* d_ws, size_t ws_size,
                              hipStream_t stream)
{
    const float* x    = (const float*)d_in[0];
    const int*   ei   = (const int*)  d_in[1];
    const float* ea   = (const float*)d_in[2];
    const float* Wm1  = (const float*)d_in[3];
    const float* bm1  = (const float*)d_in[4];
    const float* Wm2  = (const float*)d_in[5];
    const float* bm2  = (const float*)d_in[6];
    const float* Wg   = (const float*)d_in[7];
    const float* bg   = (const float*)d_in[8];
    const float* Wu1  = (const float*)d_in[9];
    const float* bu1  = (const float*)d_in[10];
    const float* Wu2  = (const float*)d_in[11];
    const float* bu2  = (const float*)d_in[12];
    const float* gmma = (const float*)d_in[13];
    const float* beta = (const float*)d_in[14];
    float* out = (float*)d_out;

    const int N = in_sizes[0] / HID;
    const int E = in_sizes[1] / 2;

    // workspace carve-up
    unsigned short* S1b  = (unsigned short*)d_ws;            // N*128 bf16
    unsigned short* Tb   = S1b + (size_t)N * HID;            // N*128 bf16
    float*          HS   = (float*)(Tb + (size_t)N * HID);   // N*128 f32
    unsigned short* W1f  = (unsigned short*)(HS + (size_t)N * HID); // 32768
    unsigned short* WgH  = W1f + 32768;
    unsigned short* Wu1H = WgH + 32768;
    unsigned short* Wu2H = Wu1H + 32768;
    float*          bcg  = (float*)(Wu2H + 16384);           // 128
    float*          bcu  = bcg + 128;                        // 128
    unsigned*       cnt  = (unsigned*)(bcu + 128);           // N
    unsigned*       cur  = cnt + N;                          // N
    uint4*          rec  = (uint4*)(cur + N);
    rec = (uint4*)(((size_t)rec + 15) & ~(size_t)15);
    size_t need_sort = (size_t)((char*)(rec + E) - (char*)d_ws);
    const bool tierA = (ws_size >= need_sort);

    // fused weights prep + cnt zero
    int zblocks = ((N + 3) / 4 + 255) / 256;
    prep_all<<<dim3(280 + zblocks), dim3(256), 0, stream>>>(
        Wm1, Wg, Wu1, Wm2, bm2, Wu2, W1f, WgH, bcg, Wu1H, bcu, Wu2H, cnt, N);

    // dense per-node S1/T + fused degree histogram
    s1t_hist_k<<<dim3((N + 63) / 64), dim3(256), 0, stream>>>(
        x, W1f, S1b, Tb, N, ei, cnt, E);

    if (tierA) {
        scan_k<<<dim3(1), dim3(1024), 0, stream>>>(cnt, cur, N);
        scatter_k<<<dim3((E + 255) / 256), dim3(256), 0, stream>>>(ei, ea, cur, rec, E);
        csr_edge_k<<<dim3(2048), dim3(256), 0, stream>>>(
            S1b, Tb, rec, cnt, cur, Wm1 + 256 * HID, bm1, HS, N);
    } else {
        hipMemsetAsync(HS, 0, (size_t)N * HID * sizeof(float), stream);
        atomic_edge_k<<<dim3(2048), dim3(256), 0, stream>>>(
            S1b, Tb, ei, ea, Wm1 + 256 * HID, bm1, HS, E);
    }

    node_mfma<<<dim3((N + 63) / 64), dim3(256), 0, stream>>>(
        x, HS, cnt, bcg, bcu,
        WgH, Wu1H, Wu2H,
        bg, bu1, bu2, gmma, beta, out, N);
}